// Round 7
// baseline (242.205 us; speedup 1.0000x reference)
//
#include <hip/hip_runtime.h>
#include <hip/hip_bf16.h>
#include <stdint.h>

#define NROW 4096
#define FDIM 512

typedef short bf16x8 __attribute__((ext_vector_type(8)));
typedef float f32x4 __attribute__((ext_vector_type(4)));
typedef float f4 __attribute__((ext_vector_type(4)));
typedef ushort u16x4 __attribute__((ext_vector_type(4)));

#define NEG_INF (-__builtin_inff())

__device__ inline ushort f2bf(float f) {
    union { float f; uint32_t u; } c{f};
    uint32_t u = c.u;
    uint32_t r = (u + 0x7FFF + ((u >> 16) & 1)) >> 16;
    return (ushort)r;
}
__device__ inline float bf2f(ushort h) {
    union { uint32_t u; float f; } c{((uint32_t)h) << 16};
    return c.f;
}
// packed bf16 pair helpers: lo = element 0, hi = element 1
__device__ inline uint32_t cvt_pk_bf16(float lo, float hi) {
    uint32_t r;
    asm("v_cvt_pk_bf16_f32 %0, %1, %2" : "=v"(r) : "v"(lo), "v"(hi));
    return r;
}
__device__ inline float up0(uint32_t p) {
    union { uint32_t u; float f; } c{p << 16}; return c.f;
}
__device__ inline float up1(uint32_t p) {
    union { uint32_t u; float f; } c{p & 0xFFFF0000u}; return c.f;
}

__device__ inline float waveReduceMax(float v) {
    #pragma unroll
    for (int o = 32; o > 0; o >>= 1) v = fmaxf(v, __shfl_xor(v, o));
    return v;
}
__device__ inline float waveReduceSum(float v) {
    #pragma unroll
    for (int o = 32; o > 0; o >>= 1) v += __shfl_xor(v, o);
    return v;
}

// ---- sorting-network primitives (descending) -------------------------------
__device__ inline void CE(float& a, float& b) {
    float mx = fmaxf(a, b);
    b = fminf(a, b);
    a = mx;
}
// Batcher odd-even mergesort, 8 elements, descending, 19 comparators
__device__ inline void sort8(float (&l)[8]) {
    CE(l[0],l[1]); CE(l[2],l[3]); CE(l[4],l[5]); CE(l[6],l[7]);
    CE(l[0],l[2]); CE(l[1],l[3]); CE(l[4],l[6]); CE(l[5],l[7]);
    CE(l[1],l[2]); CE(l[5],l[6]);
    CE(l[0],l[4]); CE(l[1],l[5]); CE(l[2],l[6]); CE(l[3],l[7]);
    CE(l[2],l[4]); CE(l[3],l[5]);
    CE(l[1],l[2]); CE(l[3],l[4]); CE(l[5],l[6]);
}
// a, b sorted desc -> a = sorted desc top-8 of union (bitonic half-merge)
__device__ inline void mergeTop8(float (&a)[8], const float (&b)[8]) {
    float t[8];
    #pragma unroll
    for (int i = 0; i < 8; i++) t[i] = fmaxf(a[i], b[7 - i]);
    CE(t[0],t[4]); CE(t[1],t[5]); CE(t[2],t[6]); CE(t[3],t[7]);
    CE(t[0],t[2]); CE(t[1],t[3]); CE(t[4],t[6]); CE(t[5],t[7]);
    CE(t[0],t[1]); CE(t[2],t[3]); CE(t[4],t[5]); CE(t[6],t[7]);
    #pragma unroll
    for (int i = 0; i < 8; i++) a[i] = t[i];
}

#define GLL16(src, dst)                                                        \
    __builtin_amdgcn_global_load_lds(                                          \
        (const __attribute__((address_space(1))) void*)(src),                  \
        (__attribute__((address_space(3))) void*)(dst), 16, 0, 0)

// ---------------------------------------------------------------------------
__global__ __launch_bounds__(64) void coef_k(const float* __restrict__ alpha,
                                             const float* __restrict__ beta,
                                             float* __restrict__ coef) {
    if (threadIdx.x == 0) {
        float a0 = alpha[0], a1 = alpha[1], a2 = alpha[2];
        float m = fmaxf(a0, fmaxf(a1, a2));
        float e0 = expf(a0 - m), e1 = expf(a1 - m), e2 = expf(a2 - m);
        float s = e0 + e1 + e2;
        coef[0] = e0 / s; coef[1] = e1 / s; coef[2] = e2 / s;
        coef[3] = beta[0];
    }
}

// ---------------------------------------------------------------------------
// per-row normalize -> xn bf16; raw cast -> xb bf16
__global__ __launch_bounds__(256) void prep_x(const float* __restrict__ x,
                                              ushort* __restrict__ xn,
                                              ushort* __restrict__ xb) {
    int row = blockIdx.x, tid = threadIdx.x;
    int lane = tid & 63, w = tid >> 6;
    const float* xr = x + (size_t)row * FDIM;
    float v0 = xr[tid], v1 = xr[tid + 256];
    float ss = v0 * v0 + v1 * v1;
    ss = waveReduceSum(ss);
    __shared__ float b4[4];
    if (lane == 0) b4[w] = ss;
    __syncthreads();
    float tot = b4[0] + b4[1] + b4[2] + b4[3];
    float inv = 1.f / fmaxf(sqrtf(tot), 1e-12f);
    size_t o = (size_t)row * FDIM + tid;
    xn[o] = f2bf(v0 * inv);  xn[o + 256] = f2bf(v1 * inv);
    xb[o] = f2bf(v0);        xb[o + 256] = f2bf(v1);
}

// ---------------------------------------------------------------------------
__global__ __launch_bounds__(256) void transpose_xb(const ushort* __restrict__ in,
                                                    ushort* __restrict__ out) {
    __shared__ ushort t[64][65];
    int lx = threadIdx.x & 63, ly = threadIdx.x >> 6;
    int c0 = blockIdx.x * 64, r0 = blockIdx.y * 64;
    #pragma unroll
    for (int i = 0; i < 16; i++)
        t[ly + 4 * i][lx] = in[(size_t)(r0 + ly + 4 * i) * FDIM + c0 + lx];
    __syncthreads();
    #pragma unroll
    for (int i = 0; i < 16; i++)
        out[(size_t)(c0 + ly + 4 * i) * NROW + r0 + lx] = t[lx][ly + 4 * i];
}

// convert + transpose both fp32 512x512 weights -> bf16 (z selects which)
__global__ __launch_bounds__(256) void convT_w2(const float* __restrict__ W0,
                                                ushort* __restrict__ T0,
                                                const float* __restrict__ W1,
                                                ushort* __restrict__ T1) {
    const float* Wf = blockIdx.z ? W1 : W0;
    ushort* WT = blockIdx.z ? T1 : T0;
    __shared__ ushort t[64][65];
    int lx = threadIdx.x & 63, ly = threadIdx.x >> 6;
    int c0 = blockIdx.x * 64, r0 = blockIdx.y * 64;
    #pragma unroll
    for (int i = 0; i < 16; i++)
        t[ly + 4 * i][lx] = f2bf(Wf[(size_t)(r0 + ly + 4 * i) * 512 + c0 + lx]);
    __syncthreads();
    #pragma unroll
    for (int i = 0; i < 16; i++)
        WT[(size_t)(c0 + ly + 4 * i) * 512 + r0 + lx] = t[lx][ly + 4 * i];
}

// ---------------------------------------------------------------------------
// C = A(MxK) * B(NxK)^T, bf16 MFMA 16x16x32, 128x128 tile, 4 waves, BK=64.
// EPI 1: fp32 C + bias[col].  EPI 3: split-K partial (z selects K-chunk 1024).
// EPI 4: bf16 C.
template <int EPI>
__global__ __launch_bounds__(256) void gemm_abT(
    const ushort* __restrict__ A, int lda,
    const ushort* __restrict__ B, int ldb,
    int Kdim, int ldc,
    float* __restrict__ Cf, ushort* __restrict__ Cb,
    const float* __restrict__ bias) {
    constexpr int BK = 64;
    constexpr int NT = 128 * BK;
    constexpr int CPR = BK / 8;               // 8 chunks of 16B per row
    constexpr int PASSES = (128 * CPR) / 256; // 4
    __shared__ __align__(16) ushort smem[2 * NT];
    ushort* As = smem;
    ushort* Bs = smem + NT;

    if constexpr (EPI == 3) {
        A += (size_t)blockIdx.z * 1024;
        B += (size_t)blockIdx.z * 1024;
        Cf += (size_t)blockIdx.z * ((size_t)NROW * 512);
    }

    const int tid = threadIdx.x;
    const int lane = tid & 63, w = tid >> 6;
    const int wr = w >> 1, wc = w & 1;
    const int m0 = blockIdx.y * 128;
    const int n0 = blockIdx.x * 128;

    f32x4 acc[4][4];
    #pragma unroll
    for (int mi = 0; mi < 4; mi++)
        #pragma unroll
        for (int ni = 0; ni < 4; ni++)
            #pragma unroll
            for (int r = 0; r < 4; r++) acc[mi][ni][r] = 0.f;

    for (int k0 = 0; k0 < Kdim; k0 += BK) {
        #pragma unroll
        for (int p = 0; p < PASSES; ++p) {
            int chunk = p * 256 + tid;
            int row = chunk / CPR;
            int kc = chunk % CPR;
            const ushort* asrc = A + (size_t)(m0 + row) * lda + k0 + kc * 8;
            const ushort* bsrc = B + (size_t)(n0 + row) * ldb + k0 + kc * 8;
            ushort* abase = As + (size_t)(p * 256 + w * 64) * 8;
            ushort* bbase = Bs + (size_t)(p * 256 + w * 64) * 8;
            GLL16(asrc, abase);
            GLL16(bsrc, bbase);
        }
        __syncthreads();
        #pragma unroll
        for (int kf = 0; kf < BK / 32; ++kf) {
            const int ko = kf * 32 + (lane >> 4) * 8;
            bf16x8 av[4], bv[4];
            #pragma unroll
            for (int mi = 0; mi < 4; mi++)
                av[mi] = *(const bf16x8*)&As[(wr * 64 + mi * 16 + (lane & 15)) * BK + ko];
            #pragma unroll
            for (int ni = 0; ni < 4; ni++)
                bv[ni] = *(const bf16x8*)&Bs[(wc * 64 + ni * 16 + (lane & 15)) * BK + ko];
            #pragma unroll
            for (int mi = 0; mi < 4; mi++)
                #pragma unroll
                for (int ni = 0; ni < 4; ni++)
                    acc[mi][ni] = __builtin_amdgcn_mfma_f32_16x16x32_bf16(
                        av[mi], bv[ni], acc[mi][ni], 0, 0, 0);
        }
        __syncthreads();
    }

    #pragma unroll
    for (int mi = 0; mi < 4; mi++) {
        #pragma unroll
        for (int ni = 0; ni < 4; ni++) {
            int col = n0 + wc * 64 + ni * 16 + (lane & 15);
            #pragma unroll
            for (int r = 0; r < 4; r++) {
                int rowg = m0 + wr * 64 + mi * 16 + (lane >> 4) * 4 + r;
                size_t off = (size_t)rowg * ldc + col;
                float v = acc[mi][ni][r];
                if constexpr (EPI == 1) {
                    Cf[off] = v + bias[col];
                } else if constexpr (EPI == 3) {
                    Cf[off] = v;
                } else {
                    Cb[off] = f2bf(v);
                }
            }
        }
    }
}

// ---------------------------------------------------------------------------
// chunk top-8: 16 rounded products (adj_bf16 * sim_bf16) -> sorted desc top-8
__device__ __attribute__((always_inline)) inline void chunk_top8(
    const f4 (&a)[4], const uint2 (&sp)[4], float (&t)[8]) {
    float u[8];
    #pragma unroll
    for (int qq = 0; qq < 2; qq++) {
        uint32_t p0 = cvt_pk_bf16(a[qq].x, a[qq].y);
        uint32_t p1 = cvt_pk_bf16(a[qq].z, a[qq].w);
        t[qq * 4 + 0] = up0(p0) * up0(sp[qq].x);
        t[qq * 4 + 1] = up1(p0) * up1(sp[qq].x);
        t[qq * 4 + 2] = up0(p1) * up0(sp[qq].y);
        t[qq * 4 + 3] = up1(p1) * up1(sp[qq].y);
    }
    #pragma unroll
    for (int qq = 0; qq < 2; qq++) {
        const int q = 2 + qq;
        uint32_t p0 = cvt_pk_bf16(a[q].x, a[q].y);
        uint32_t p1 = cvt_pk_bf16(a[q].z, a[q].w);
        u[qq * 4 + 0] = up0(p0) * up0(sp[q].x);
        u[qq * 4 + 1] = up1(p0) * up1(sp[q].x);
        u[qq * 4 + 2] = up0(p1) * up0(sp[q].y);
        u[qq * 4 + 3] = up1(p1) * up1(sp[q].y);
    }
    sort8(t);
    sort8(u);
    mergeTop8(t, u);
}

// threshold (8th largest of adj*sim over the row) for hop K — wave-local.
template <int K>
__device__ __attribute__((always_inline)) inline float hop_threshold(
    const float* __restrict__ arow, const ushort* __restrict__ srow,
    int loff) {
    const size_t hopstride = (size_t)NROW * NROW;
    float l[8];
    #pragma unroll
    for (int c = 0; c < 4; ++c) {
        f4 a[4];
        uint2 sp[4];
        #pragma unroll
        for (int q = 0; q < 4; q++)
            a[q] = *(const f4*)(arow + K * hopstride + c * 1024 + q * 256 + loff);
        #pragma unroll
        for (int q = 0; q < 4; q++)
            sp[q] = *(const uint2*)(srow + c * 1024 + q * 256 + loff);
        float t[8];
        chunk_top8(a, sp, t);
        if (c == 0) {
            #pragma unroll
            for (int i = 0; i < 8; i++) l[i] = t[i];
        } else {
            mergeTop8(l, t);
        }
    }
    // wave top-8: 6-level butterfly merge tree (all lanes converge)
    #pragma unroll
    for (int lvl = 0; lvl < 6; lvl++) {
        float b[8];
        #pragma unroll
        for (int i = 0; i < 8; i++) b[i] = __shfl_xor(l[i], 1 << lvl);
        mergeTop8(l, b);
    }
    return l[7];
}

// ---------------------------------------------------------------------------
// topk + build M — ONE WAVE PER ROW, no barriers, no LDS, no cross-wave.
// Block = 256 = 4 independent waves (4 rows); grid 1024. Lane owns 64 cols
// (4 chunks x 16: j = c*1024 + q*256 + lane*4 + e).
// Phase 1: per hop, stream 4 chunks keeping a running top-8 (2xsort8+merge),
// then one 6-level shfl_xor merge tree -> threshold (template-instantiated
// scalars thr0/1/2 — no runtime-indexed array, no scratch).
// Phase 2: stream chunks; re-read adj (L3-hot) + rmask + sim; accumulate
// macc = sum_k aksq*adj*mask; write M = sim*macc (bf16).
// r3/r5/r6 all plateaued 131-136us: 4-wave barrier convoy + 4x-redundant
// tree. This removes every sync. Spill tripwire: WRITE_SIZE must stay 32MB.
__global__ __launch_bounds__(256) void topk_build_M(
    const ushort* __restrict__ simb, const float* __restrict__ adj,
    const float* __restrict__ rmask, const float* __restrict__ coef,
    ushort* __restrict__ Mout) {
    const int tid = threadIdx.x;
    const int lane = tid & 63;
    const int w = tid >> 6;
    const int row = blockIdx.x * 4 + w;
    const int loff = lane * 4;
    const size_t hopstride = (size_t)NROW * NROW;

    const ushort* srow = simb + (size_t)row * NROW;
    const float* arow = adj + (size_t)row * NROW;
    const float* rrow = rmask + (size_t)row * NROW;

    // phase 1: per-hop thresholds
    const float thr0 = hop_threshold<0>(arow, srow, loff);
    const float thr1 = hop_threshold<1>(arow, srow, loff);
    const float thr2 = hop_threshold<2>(arow, srow, loff);

    const float c0 = coef[0], c1 = coef[1], c2 = coef[2];

    // phase 2: streaming mask-apply + M write, chunk by chunk
    #pragma unroll 1
    for (int c = 0; c < 4; ++c) {
        uint2 sp[4];
        #pragma unroll
        for (int q = 0; q < 4; q++)
            sp[q] = *(const uint2*)(srow + c * 1024 + q * 256 + loff);

        float macc[4][4];
        #pragma unroll
        for (int q = 0; q < 4; q++)
            #pragma unroll
            for (int e = 0; e < 4; e++) macc[q][e] = 0.f;

        #pragma unroll
        for (int k = 0; k < 3; ++k) {
            const float ak = (k == 0) ? c0 : (k == 1) ? c1 : c2;
            const float thr = (k == 0) ? thr0 : (k == 1) ? thr1 : thr2;
            const float aksq = ak * ak;
            f4 a[4], rv[4];
            #pragma unroll
            for (int q = 0; q < 4; q++)
                rv[q] = *(const f4*)(rrow + k * hopstride + c * 1024 + q * 256 + loff);
            #pragma unroll
            for (int q = 0; q < 4; q++)
                a[q] = *(const f4*)(arow + k * hopstride + c * 1024 + q * 256 + loff);
            #pragma unroll
            for (int q = 0; q < 4; q++) {
                uint32_t p0 = cvt_pk_bf16(a[q].x, a[q].y);
                uint32_t p1 = cvt_pk_bf16(a[q].z, a[q].w);
                float av0 = up0(p0), av1 = up1(p0);
                float av2 = up0(p1), av3 = up1(p1);
                float s0 = up0(sp[q].x), s1 = up1(sp[q].x);
                float s2 = up0(sp[q].y), s3 = up1(sp[q].y);
                bool m0 = (rv[q].x < 0.5f) || (av0 * s0 >= thr);
                bool m1 = (rv[q].y < 0.5f) || (av1 * s1 >= thr);
                bool m2 = (rv[q].z < 0.5f) || (av2 * s2 >= thr);
                bool m3 = (rv[q].w < 0.5f) || (av3 * s3 >= thr);
                macc[q][0] += m0 ? aksq * av0 : 0.f;
                macc[q][1] += m1 ? aksq * av1 : 0.f;
                macc[q][2] += m2 ? aksq * av2 : 0.f;
                macc[q][3] += m3 ? aksq * av3 : 0.f;
            }
        }

        ushort* mrow = Mout + (size_t)row * NROW + c * 1024 + loff;
        #pragma unroll
        for (int q = 0; q < 4; q++) {
            u16x4 o;
            o[0] = f2bf(up0(sp[q].x) * macc[q][0]);
            o[1] = f2bf(up1(sp[q].x) * macc[q][1]);
            o[2] = f2bf(up0(sp[q].y) * macc[q][2]);
            o[3] = f2bf(up1(sp[q].y) * macc[q][3]);
            *(u16x4*)(mrow + q * 256) = o;
        }
    }
}

// ---------------------------------------------------------------------------
// H = relu(cb*Hlow + (1-cb)*sum_z parts[z]) -> bf16
__global__ __launch_bounds__(256) void reduce_relu(
    const float* __restrict__ parts, const float* __restrict__ hlow,
    const float* __restrict__ coef, ushort* __restrict__ Hb) {
    const size_t i = (size_t)blockIdx.x * 256 + threadIdx.x;  // f4 index
    const f4* p4 = (const f4*)parts;
    f4 s = p4[i];
    #pragma unroll
    for (int z = 1; z < 4; z++) s += p4[(size_t)z * 524288 + i];
    f4 hl = ((const f4*)hlow)[i];
    float cb = coef[3];
    u16x4 o;
    #pragma unroll
    for (int c = 0; c < 4; c++) {
        float h = cb * hl[c] + (1.f - cb) * s[c];
        o[c] = f2bf(fmaxf(h, 0.f));
    }
    *((u16x4*)Hb + i) = o;
}

// ---------------------------------------------------------------------------
__global__ __launch_bounds__(256) void logsoftmax_k(const float* __restrict__ L,
                                                    float* __restrict__ out) {
    int row = blockIdx.x, tid = threadIdx.x;
    int lane = tid & 63, w = tid >> 6;
    const float* lr = L + (size_t)row * 512;
    float v0 = lr[tid], v1 = lr[tid + 256];
    __shared__ float bm[4], bs[4];
    float m = fmaxf(v0, v1);
    m = waveReduceMax(m);
    if (lane == 0) bm[w] = m;
    __syncthreads();
    float M = fmaxf(fmaxf(bm[0], bm[1]), fmaxf(bm[2], bm[3]));
    float s = expf(v0 - M) + expf(v1 - M);
    s = waveReduceSum(s);
    if (lane == 0) bs[w] = s;
    __syncthreads();
    float S = bs[0] + bs[1] + bs[2] + bs[3];
    float lse = M + logf(S);
    float* orow = out + (size_t)row * 512;
    orow[tid] = v0 - lse;
    orow[tid + 256] = v1 - lse;
}

// ---------------------------------------------------------------------------
extern "C" void kernel_launch(void* const* d_in, const int* in_sizes, int n_in,
                              void* d_out, int out_size, void* d_ws, size_t ws_size,
                              hipStream_t stream) {
    const float* x     = (const float*)d_in[0];
    const float* adj   = (const float*)d_in[1];
    const float* rmask = (const float*)d_in[2];
    const float* W_in  = (const float*)d_in[3];
    const float* b_in  = (const float*)d_in[4];
    const float* W_out = (const float*)d_in[5];
    const float* b_out = (const float*)d_in[6];
    const float* alpha = (const float*)d_in[7];
    const float* beta  = (const float*)d_in[8];
    float* out = (float*)d_out;

    const size_t MB = 1024 * 1024;
    char* wsb = (char*)d_ws;
    // [0,32):  simb bf16 -> (dead after topk) -> parts fp32 4x8MB -> logits [0,8)
    // [32,64): Mb bf16
    // [64,68): xn bf16    [68,72): xb bf16    [72,76): xbT bf16
    // [76,76.5): WinT     [76.5,77): WoutT
    // [77,85): Hlow fp32  [85,89): Hb bf16    [89): coef
    ushort* simb   = (ushort*)wsb;
    float*  parts  = (float*)wsb;
    float*  logits = (float*)wsb;
    ushort* Mb     = (ushort*)(wsb + 32 * MB);
    ushort* xn     = (ushort*)(wsb + 64 * MB);
    ushort* xb     = (ushort*)(wsb + 68 * MB);
    ushort* xbT    = (ushort*)(wsb + 72 * MB);
    ushort* WinT   = (ushort*)(wsb + 76 * MB);
    ushort* WoutT  = (ushort*)(wsb + 76 * MB + 512 * 1024);
    float*  Hlow   = (float*)(wsb + 77 * MB);
    ushort* Hb     = (ushort*)(wsb + 85 * MB);
    float*  coef   = (float*)(wsb + 89 * MB);

    coef_k<<<1, 64, 0, stream>>>(alpha, beta, coef);
    prep_x<<<NROW, 256, 0, stream>>>(x, xn, xb);
    transpose_xb<<<dim3(8, 64), 256, 0, stream>>>(xb, xbT);
    convT_w2<<<dim3(8, 8, 2), 256, 0, stream>>>(W_in, WinT, W_out, WoutT);

    // sim = xn @ xn^T  -> bf16
    gemm_abT<4><<<dim3(32, 32), 256, 0, stream>>>(
        xn, FDIM, xn, FDIM, FDIM, NROW, nullptr, simb, nullptr);

    // combined masked adjacency M (bf16)
    topk_build_M<<<NROW / 4, 256, 0, stream>>>(simb, adj, rmask, coef, Mb);

    // H_low = x @ W_in + b_in
    gemm_abT<1><<<dim3(4, 32), 256, 0, stream>>>(
        xb, FDIM, WinT, FDIM, FDIM, 512, Hlow, nullptr, b_in);

    // split-K=4: parts[z] = M[:, z*1024:+1024] @ x[z*1024:+1024, :]
    gemm_abT<3><<<dim3(4, 32, 4), 256, 0, stream>>>(
        Mb, NROW, xbT, NROW, 1024, 512, parts, nullptr, nullptr);

    // H = relu(b*Hlow + (1-b)*sum parts) -> bf16
    reduce_relu<<<2048, 256, 0, stream>>>(parts, Hlow, coef, Hb);

    // logits = H @ W_out + b_out
    gemm_abT<1><<<dim3(4, 32), 256, 0, stream>>>(
        Hb, 512, WoutT, 512, 512, 512, logits, nullptr, b_out);

    logsoftmax_k<<<NROW, 256, 0, stream>>>(logits, out);
}

// Round 8
// 223.081 us; speedup vs baseline: 1.0857x; 1.0857x over previous
//
#include <hip/hip_runtime.h>
#include <hip/hip_bf16.h>
#include <stdint.h>

#define NROW 4096
#define FDIM 512

typedef short bf16x8 __attribute__((ext_vector_type(8)));
typedef float f32x4 __attribute__((ext_vector_type(4)));
typedef float f4 __attribute__((ext_vector_type(4)));
typedef ushort u16x4 __attribute__((ext_vector_type(4)));

#define NEG_INF (-__builtin_inff())

__device__ inline ushort f2bf(float f) {
    union { float f; uint32_t u; } c{f};
    uint32_t u = c.u;
    uint32_t r = (u + 0x7FFF + ((u >> 16) & 1)) >> 16;
    return (ushort)r;
}
__device__ inline float bf2f(ushort h) {
    union { uint32_t u; float f; } c{((uint32_t)h) << 16};
    return c.f;
}
// packed bf16 pair helpers: lo = element 0, hi = element 1
__device__ inline uint32_t cvt_pk_bf16(float lo, float hi) {
    uint32_t r;
    asm("v_cvt_pk_bf16_f32 %0, %1, %2" : "=v"(r) : "v"(lo), "v"(hi));
    return r;
}
__device__ inline float up0(uint32_t p) {
    union { uint32_t u; float f; } c{p << 16}; return c.f;
}
__device__ inline float up1(uint32_t p) {
    union { uint32_t u; float f; } c{p & 0xFFFF0000u}; return c.f;
}

__device__ inline float waveReduceMax(float v) {
    #pragma unroll
    for (int o = 32; o > 0; o >>= 1) v = fmaxf(v, __shfl_xor(v, o));
    return v;
}
__device__ inline float waveReduceSum(float v) {
    #pragma unroll
    for (int o = 32; o > 0; o >>= 1) v += __shfl_xor(v, o);
    return v;
}

// ---- sorting-network primitives (descending) -------------------------------
__device__ inline void CE(float& a, float& b) {
    float mx = fmaxf(a, b);
    b = fminf(a, b);
    a = mx;
}
// Batcher odd-even mergesort, 8 elements, descending, 19 comparators
__device__ inline void sort8(float (&l)[8]) {
    CE(l[0],l[1]); CE(l[2],l[3]); CE(l[4],l[5]); CE(l[6],l[7]);
    CE(l[0],l[2]); CE(l[1],l[3]); CE(l[4],l[6]); CE(l[5],l[7]);
    CE(l[1],l[2]); CE(l[5],l[6]);
    CE(l[0],l[4]); CE(l[1],l[5]); CE(l[2],l[6]); CE(l[3],l[7]);
    CE(l[2],l[4]); CE(l[3],l[5]);
    CE(l[1],l[2]); CE(l[3],l[4]); CE(l[5],l[6]);
}
// a, b sorted desc -> a = sorted desc top-8 of union (bitonic half-merge)
__device__ inline void mergeTop8(float (&a)[8], const float (&b)[8]) {
    float t[8];
    #pragma unroll
    for (int i = 0; i < 8; i++) t[i] = fmaxf(a[i], b[7 - i]);
    CE(t[0],t[4]); CE(t[1],t[5]); CE(t[2],t[6]); CE(t[3],t[7]);
    CE(t[0],t[2]); CE(t[1],t[3]); CE(t[4],t[6]); CE(t[5],t[7]);
    CE(t[0],t[1]); CE(t[2],t[3]); CE(t[4],t[5]); CE(t[6],t[7]);
    #pragma unroll
    for (int i = 0; i < 8; i++) a[i] = t[i];
}

#define GLL16(src, dst)                                                        \
    __builtin_amdgcn_global_load_lds(                                          \
        (const __attribute__((address_space(1))) void*)(src),                  \
        (__attribute__((address_space(3))) void*)(dst), 16, 0, 0)

// ---------------------------------------------------------------------------
__global__ __launch_bounds__(64) void coef_k(const float* __restrict__ alpha,
                                             const float* __restrict__ beta,
                                             float* __restrict__ coef) {
    if (threadIdx.x == 0) {
        float a0 = alpha[0], a1 = alpha[1], a2 = alpha[2];
        float m = fmaxf(a0, fmaxf(a1, a2));
        float e0 = expf(a0 - m), e1 = expf(a1 - m), e2 = expf(a2 - m);
        float s = e0 + e1 + e2;
        coef[0] = e0 / s; coef[1] = e1 / s; coef[2] = e2 / s;
        coef[3] = beta[0];
    }
}

// ---------------------------------------------------------------------------
// per-row normalize -> xn bf16; raw cast -> xb bf16
__global__ __launch_bounds__(256) void prep_x(const float* __restrict__ x,
                                              ushort* __restrict__ xn,
                                              ushort* __restrict__ xb) {
    int row = blockIdx.x, tid = threadIdx.x;
    int lane = tid & 63, w = tid >> 6;
    const float* xr = x + (size_t)row * FDIM;
    float v0 = xr[tid], v1 = xr[tid + 256];
    float ss = v0 * v0 + v1 * v1;
    ss = waveReduceSum(ss);
    __shared__ float b4[4];
    if (lane == 0) b4[w] = ss;
    __syncthreads();
    float tot = b4[0] + b4[1] + b4[2] + b4[3];
    float inv = 1.f / fmaxf(sqrtf(tot), 1e-12f);
    size_t o = (size_t)row * FDIM + tid;
    xn[o] = f2bf(v0 * inv);  xn[o + 256] = f2bf(v1 * inv);
    xb[o] = f2bf(v0);        xb[o + 256] = f2bf(v1);
}

// ---------------------------------------------------------------------------
__global__ __launch_bounds__(256) void transpose_xb(const ushort* __restrict__ in,
                                                    ushort* __restrict__ out) {
    __shared__ ushort t[64][65];
    int lx = threadIdx.x & 63, ly = threadIdx.x >> 6;
    int c0 = blockIdx.x * 64, r0 = blockIdx.y * 64;
    #pragma unroll
    for (int i = 0; i < 16; i++)
        t[ly + 4 * i][lx] = in[(size_t)(r0 + ly + 4 * i) * FDIM + c0 + lx];
    __syncthreads();
    #pragma unroll
    for (int i = 0; i < 16; i++)
        out[(size_t)(c0 + ly + 4 * i) * NROW + r0 + lx] = t[lx][ly + 4 * i];
}

// convert + transpose both fp32 512x512 weights -> bf16 (z selects which)
__global__ __launch_bounds__(256) void convT_w2(const float* __restrict__ W0,
                                                ushort* __restrict__ T0,
                                                const float* __restrict__ W1,
                                                ushort* __restrict__ T1) {
    const float* Wf = blockIdx.z ? W1 : W0;
    ushort* WT = blockIdx.z ? T1 : T0;
    __shared__ ushort t[64][65];
    int lx = threadIdx.x & 63, ly = threadIdx.x >> 6;
    int c0 = blockIdx.x * 64, r0 = blockIdx.y * 64;
    #pragma unroll
    for (int i = 0; i < 16; i++)
        t[ly + 4 * i][lx] = f2bf(Wf[(size_t)(r0 + ly + 4 * i) * 512 + c0 + lx]);
    __syncthreads();
    #pragma unroll
    for (int i = 0; i < 16; i++)
        WT[(size_t)(c0 + ly + 4 * i) * 512 + r0 + lx] = t[lx][ly + 4 * i];
}

// ---------------------------------------------------------------------------
// C = A(MxK) * B(NxK)^T, bf16 MFMA 16x16x32, 128x128 tile, 4 waves, BK=64.
// EPI 1: fp32 C + bias[col].  EPI 3: split-K partial (z selects K-chunk 1024).
// EPI 4: bf16 C.
template <int EPI>
__global__ __launch_bounds__(256) void gemm_abT(
    const ushort* __restrict__ A, int lda,
    const ushort* __restrict__ B, int ldb,
    int Kdim, int ldc,
    float* __restrict__ Cf, ushort* __restrict__ Cb,
    const float* __restrict__ bias) {
    constexpr int BK = 64;
    constexpr int NT = 128 * BK;
    constexpr int CPR = BK / 8;               // 8 chunks of 16B per row
    constexpr int PASSES = (128 * CPR) / 256; // 4
    __shared__ __align__(16) ushort smem[2 * NT];
    ushort* As = smem;
    ushort* Bs = smem + NT;

    if constexpr (EPI == 3) {
        A += (size_t)blockIdx.z * 1024;
        B += (size_t)blockIdx.z * 1024;
        Cf += (size_t)blockIdx.z * ((size_t)NROW * 512);
    }

    const int tid = threadIdx.x;
    const int lane = tid & 63, w = tid >> 6;
    const int wr = w >> 1, wc = w & 1;
    const int m0 = blockIdx.y * 128;
    const int n0 = blockIdx.x * 128;

    f32x4 acc[4][4];
    #pragma unroll
    for (int mi = 0; mi < 4; mi++)
        #pragma unroll
        for (int ni = 0; ni < 4; ni++)
            #pragma unroll
            for (int r = 0; r < 4; r++) acc[mi][ni][r] = 0.f;

    for (int k0 = 0; k0 < Kdim; k0 += BK) {
        #pragma unroll
        for (int p = 0; p < PASSES; ++p) {
            int chunk = p * 256 + tid;
            int row = chunk / CPR;
            int kc = chunk % CPR;
            const ushort* asrc = A + (size_t)(m0 + row) * lda + k0 + kc * 8;
            const ushort* bsrc = B + (size_t)(n0 + row) * ldb + k0 + kc * 8;
            ushort* abase = As + (size_t)(p * 256 + w * 64) * 8;
            ushort* bbase = Bs + (size_t)(p * 256 + w * 64) * 8;
            GLL16(asrc, abase);
            GLL16(bsrc, bbase);
        }
        __syncthreads();
        #pragma unroll
        for (int kf = 0; kf < BK / 32; ++kf) {
            const int ko = kf * 32 + (lane >> 4) * 8;
            bf16x8 av[4], bv[4];
            #pragma unroll
            for (int mi = 0; mi < 4; mi++)
                av[mi] = *(const bf16x8*)&As[(wr * 64 + mi * 16 + (lane & 15)) * BK + ko];
            #pragma unroll
            for (int ni = 0; ni < 4; ni++)
                bv[ni] = *(const bf16x8*)&Bs[(wc * 64 + ni * 16 + (lane & 15)) * BK + ko];
            #pragma unroll
            for (int mi = 0; mi < 4; mi++)
                #pragma unroll
                for (int ni = 0; ni < 4; ni++)
                    acc[mi][ni] = __builtin_amdgcn_mfma_f32_16x16x32_bf16(
                        av[mi], bv[ni], acc[mi][ni], 0, 0, 0);
        }
        __syncthreads();
    }

    #pragma unroll
    for (int mi = 0; mi < 4; mi++) {
        #pragma unroll
        for (int ni = 0; ni < 4; ni++) {
            int col = n0 + wc * 64 + ni * 16 + (lane & 15);
            #pragma unroll
            for (int r = 0; r < 4; r++) {
                int rowg = m0 + wr * 64 + mi * 16 + (lane >> 4) * 4 + r;
                size_t off = (size_t)rowg * ldc + col;
                float v = acc[mi][ni][r];
                if constexpr (EPI == 1) {
                    Cf[off] = v + bias[col];
                } else if constexpr (EPI == 3) {
                    Cf[off] = v;
                } else {
                    Cb[off] = f2bf(v);
                }
            }
        }
    }
}

// ---------------------------------------------------------------------------
// topk + build M — FUSED 3-HOP version. 4 waves per row (wave w owns cols
// [w*1024,(w+1)*1024), lane owns 16: j = w*1024 + q*256 + lane*4 + e).
// All 28 dwordx4 for the row issue upfront (sim, rmask x3, adj x3); adj is
// kept packed-bf16 in registers (read ONCE — r7's re-read cost +115MB HBM).
// The 3 hops' sort chains + wave trees run INTERLEAVED in one straight-line
// region (3x ILP on the ~900cy dependent chain that r3/r5/r6 ran serially),
// with ONE __syncthreads total (was 3).
// Spill tripwire: WRITE_SIZE must stay 32768 KB (r4 lesson).
__global__ __launch_bounds__(256) void topk_build_M(
    const ushort* __restrict__ simb, const float* __restrict__ adj,
    const float* __restrict__ rmask, const float* __restrict__ coef,
    ushort* __restrict__ Mout) {
    const int tid = threadIdx.x;
    const int lane = tid & 63;
    const int w = tid >> 6;
    const int row = blockIdx.x;
    __shared__ float wl[3][4][8];
    const int cbase = w * 1024 + lane * 4;
    const size_t hs = (size_t)NROW * NROW;

    const ushort* srow = simb + (size_t)row * NROW + cbase;
    const float* arow = adj + (size_t)row * NROW + cbase;
    const float* rrow = rmask + (size_t)row * NROW + cbase;

    // ---- issue ALL loads for this row's slice ------------------------------
    uint2 svp[4];
    #pragma unroll
    for (int q = 0; q < 4; q++) svp[q] = *(const uint2*)(srow + q * 256);
    f4 rv[3][4];
    #pragma unroll
    for (int k = 0; k < 3; k++)
        #pragma unroll
        for (int q = 0; q < 4; q++)
            rv[k][q] = *(const f4*)(rrow + (size_t)k * hs + q * 256);
    f4 av[3][4];
    #pragma unroll
    for (int k = 0; k < 3; k++)
        #pragma unroll
        for (int q = 0; q < 4; q++)
            av[k][q] = *(const f4*)(arow + (size_t)k * hs + q * 256);

    // retain bits (frees rmask regs as loads land)
    uint32_t rb[3];
    #pragma unroll
    for (int k = 0; k < 3; k++) {
        uint32_t b = 0;
        #pragma unroll
        for (int q = 0; q < 4; q++) {
            b |= (rv[k][q].x < 0.5f ? 1u : 0u) << (q * 4 + 0);
            b |= (rv[k][q].y < 0.5f ? 1u : 0u) << (q * 4 + 1);
            b |= (rv[k][q].z < 0.5f ? 1u : 0u) << (q * 4 + 2);
            b |= (rv[k][q].w < 0.5f ? 1u : 0u) << (q * 4 + 3);
        }
        rb[k] = b;
    }

    // pack adj to bf16 (frees fp32 adj regs)
    uint2 avp[3][4];
    #pragma unroll
    for (int k = 0; k < 3; k++)
        #pragma unroll
        for (int q = 0; q < 4; q++) {
            avp[k][q].x = cvt_pk_bf16(av[k][q].x, av[k][q].y);
            avp[k][q].y = cvt_pk_bf16(av[k][q].z, av[k][q].w);
        }

    // ---- per-lane top-8, 3 independent chains (ILP 3) ----------------------
    float l[3][8];
    #pragma unroll
    for (int k = 0; k < 3; k++) {
        float t[8], u[8];
        #pragma unroll
        for (int qq = 0; qq < 2; qq++) {
            t[qq * 4 + 0] = up0(avp[k][qq].x) * up0(svp[qq].x);
            t[qq * 4 + 1] = up1(avp[k][qq].x) * up1(svp[qq].x);
            t[qq * 4 + 2] = up0(avp[k][qq].y) * up0(svp[qq].y);
            t[qq * 4 + 3] = up1(avp[k][qq].y) * up1(svp[qq].y);
        }
        #pragma unroll
        for (int qq = 0; qq < 2; qq++) {
            const int q = 2 + qq;
            u[qq * 4 + 0] = up0(avp[k][q].x) * up0(svp[q].x);
            u[qq * 4 + 1] = up1(avp[k][q].x) * up1(svp[q].x);
            u[qq * 4 + 2] = up0(avp[k][q].y) * up0(svp[q].y);
            u[qq * 4 + 3] = up1(avp[k][q].y) * up1(svp[q].y);
        }
        sort8(t);
        sort8(u);
        mergeTop8(t, u);
        #pragma unroll
        for (int i = 0; i < 8; i++) l[k][i] = t[i];
    }

    // ---- wave top-8: 6-level tree, all 3 hops per level (ILP 3) ------------
    #pragma unroll
    for (int lvl = 0; lvl < 6; lvl++) {
        float b[3][8];
        #pragma unroll
        for (int k = 0; k < 3; k++)
            #pragma unroll
            for (int i = 0; i < 8; i++) b[k][i] = __shfl_xor(l[k][i], 1 << lvl);
        #pragma unroll
        for (int k = 0; k < 3; k++) mergeTop8(l[k], b[k]);
    }

    // ---- cross-wave: one LDS exchange, one barrier -------------------------
    if (lane < 8) {
        wl[0][w][lane] = l[0][lane];
        wl[1][w][lane] = l[1][lane];
        wl[2][w][lane] = l[2][lane];
    }
    __syncthreads();
    #pragma unroll
    for (int ww = 0; ww < 4; ww++) {
        if (ww != w) {
            #pragma unroll
            for (int k = 0; k < 3; k++) {
                float b[8];
                #pragma unroll
                for (int i = 0; i < 8; i++) b[i] = wl[k][ww][i];
                mergeTop8(l[k], b);
            }
        }
    }
    const float thr0 = l[0][7], thr1 = l[1][7], thr2 = l[2][7];
    const float c0 = coef[0], c1 = coef[1], c2 = coef[2];

    // ---- fused mask pass (all register-resident) ---------------------------
    float macc[4][4];
    #pragma unroll
    for (int q = 0; q < 4; q++)
        #pragma unroll
        for (int e = 0; e < 4; e++) macc[q][e] = 0.f;

    #pragma unroll
    for (int k = 0; k < 3; k++) {
        const float ak = (k == 0) ? c0 : (k == 1) ? c1 : c2;
        const float thr = (k == 0) ? thr0 : (k == 1) ? thr1 : thr2;
        const float aksq = ak * ak;
        const uint32_t rbk = rb[k];
        #pragma unroll
        for (int q = 0; q < 4; q++) {
            float a0 = up0(avp[k][q].x), a1 = up1(avp[k][q].x);
            float a2 = up0(avp[k][q].y), a3 = up1(avp[k][q].y);
            float s0 = up0(svp[q].x), s1 = up1(svp[q].x);
            float s2 = up0(svp[q].y), s3 = up1(svp[q].y);
            bool m0 = ((rbk >> (q * 4 + 0)) & 1) || (a0 * s0 >= thr);
            bool m1 = ((rbk >> (q * 4 + 1)) & 1) || (a1 * s1 >= thr);
            bool m2 = ((rbk >> (q * 4 + 2)) & 1) || (a2 * s2 >= thr);
            bool m3 = ((rbk >> (q * 4 + 3)) & 1) || (a3 * s3 >= thr);
            macc[q][0] += m0 ? aksq * a0 : 0.f;
            macc[q][1] += m1 ? aksq * a1 : 0.f;
            macc[q][2] += m2 ? aksq * a2 : 0.f;
            macc[q][3] += m3 ? aksq * a3 : 0.f;
        }
    }

    ushort* mrow = Mout + (size_t)row * NROW + cbase;
    #pragma unroll
    for (int q = 0; q < 4; q++) {
        u16x4 o;
        o[0] = f2bf(up0(svp[q].x) * macc[q][0]);
        o[1] = f2bf(up1(svp[q].x) * macc[q][1]);
        o[2] = f2bf(up0(svp[q].y) * macc[q][2]);
        o[3] = f2bf(up1(svp[q].y) * macc[q][3]);
        *(u16x4*)(mrow + q * 256) = o;
    }
}

// ---------------------------------------------------------------------------
// H = relu(cb*Hlow + (1-cb)*sum_z parts[z]) -> bf16
__global__ __launch_bounds__(256) void reduce_relu(
    const float* __restrict__ parts, const float* __restrict__ hlow,
    const float* __restrict__ coef, ushort* __restrict__ Hb) {
    const size_t i = (size_t)blockIdx.x * 256 + threadIdx.x;  // f4 index
    const f4* p4 = (const f4*)parts;
    f4 s = p4[i];
    #pragma unroll
    for (int z = 1; z < 4; z++) s += p4[(size_t)z * 524288 + i];
    f4 hl = ((const f4*)hlow)[i];
    float cb = coef[3];
    u16x4 o;
    #pragma unroll
    for (int c = 0; c < 4; c++) {
        float h = cb * hl[c] + (1.f - cb) * s[c];
        o[c] = f2bf(fmaxf(h, 0.f));
    }
    *((u16x4*)Hb + i) = o;
}

// ---------------------------------------------------------------------------
__global__ __launch_bounds__(256) void logsoftmax_k(const float* __restrict__ L,
                                                    float* __restrict__ out) {
    int row = blockIdx.x, tid = threadIdx.x;
    int lane = tid & 63, w = tid >> 6;
    const float* lr = L + (size_t)row * 512;
    float v0 = lr[tid], v1 = lr[tid + 256];
    __shared__ float bm[4], bs[4];
    float m = fmaxf(v0, v1);
    m = waveReduceMax(m);
    if (lane == 0) bm[w] = m;
    __syncthreads();
    float M = fmaxf(fmaxf(bm[0], bm[1]), fmaxf(bm[2], bm[3]));
    float s = expf(v0 - M) + expf(v1 - M);
    s = waveReduceSum(s);
    if (lane == 0) bs[w] = s;
    __syncthreads();
    float S = bs[0] + bs[1] + bs[2] + bs[3];
    float lse = M + logf(S);
    float* orow = out + (size_t)row * 512;
    orow[tid] = v0 - lse;
    orow[tid + 256] = v1 - lse;
}

// ---------------------------------------------------------------------------
extern "C" void kernel_launch(void* const* d_in, const int* in_sizes, int n_in,
                              void* d_out, int out_size, void* d_ws, size_t ws_size,
                              hipStream_t stream) {
    const float* x     = (const float*)d_in[0];
    const float* adj   = (const float*)d_in[1];
    const float* rmask = (const float*)d_in[2];
    const float* W_in  = (const float*)d_in[3];
    const float* b_in  = (const float*)d_in[4];
    const float* W_out = (const float*)d_in[5];
    const float* b_out = (const float*)d_in[6];
    const float* alpha = (const float*)d_in[7];
    const float* beta  = (const float*)d_in[8];
    float* out = (float*)d_out;

    const size_t MB = 1024 * 1024;
    char* wsb = (char*)d_ws;
    // [0,32):  simb bf16 -> (dead after topk) -> parts fp32 4x8MB -> logits [0,8)
    // [32,64): Mb bf16
    // [64,68): xn bf16    [68,72): xb bf16    [72,76): xbT bf16
    // [76,76.5): WinT     [76.5,77): WoutT
    // [77,85): Hlow fp32  [85,89): Hb bf16    [89): coef
    ushort* simb   = (ushort*)wsb;
    float*  parts  = (float*)wsb;
    float*  logits = (float*)wsb;
    ushort* Mb     = (ushort*)(wsb + 32 * MB);
    ushort* xn     = (ushort*)(wsb + 64 * MB);
    ushort* xb     = (ushort*)(wsb + 68 * MB);
    ushort* xbT    = (ushort*)(wsb + 72 * MB);
    ushort* WinT   = (ushort*)(wsb + 76 * MB);
    ushort* WoutT  = (ushort*)(wsb + 76 * MB + 512 * 1024);
    float*  Hlow   = (float*)(wsb + 77 * MB);
    ushort* Hb     = (ushort*)(wsb + 85 * MB);
    float*  coef   = (float*)(wsb + 89 * MB);

    coef_k<<<1, 64, 0, stream>>>(alpha, beta, coef);
    prep_x<<<NROW, 256, 0, stream>>>(x, xn, xb);
    transpose_xb<<<dim3(8, 64), 256, 0, stream>>>(xb, xbT);
    convT_w2<<<dim3(8, 8, 2), 256, 0, stream>>>(W_in, WinT, W_out, WoutT);

    // sim = xn @ xn^T  -> bf16
    gemm_abT<4><<<dim3(32, 32), 256, 0, stream>>>(
        xn, FDIM, xn, FDIM, FDIM, NROW, nullptr, simb, nullptr);

    // combined masked adjacency M (bf16)
    topk_build_M<<<NROW, 256, 0, stream>>>(simb, adj, rmask, coef, Mb);

    // H_low = x @ W_in + b_in
    gemm_abT<1><<<dim3(4, 32), 256, 0, stream>>>(
        xb, FDIM, WinT, FDIM, FDIM, 512, Hlow, nullptr, b_in);

    // split-K=4: parts[z] = M[:, z*1024:+1024] @ x[z*1024:+1024, :]
    gemm_abT<3><<<dim3(4, 32, 4), 256, 0, stream>>>(
        Mb, NROW, xbT, NROW, 1024, 512, parts, nullptr, nullptr);

    // H = relu(b*Hlow + (1-b)*sum parts) -> bf16
    reduce_relu<<<2048, 256, 0, stream>>>(parts, Hlow, coef, Hb);

    // logits = H @ W_out + b_out
    gemm_abT<1><<<dim3(4, 32), 256, 0, stream>>>(
        Hb, 512, WoutT, 512, 512, 512, logits, nullptr, b_out);

    logsoftmax_k<<<NROW, 256, 0, stream>>>(logits, out);
}

// Round 9
// 213.541 us; speedup vs baseline: 1.1342x; 1.0447x over previous
//
#include <hip/hip_runtime.h>
#include <hip/hip_bf16.h>
#include <stdint.h>

#define NROW 4096
#define FDIM 512

typedef short bf16x8 __attribute__((ext_vector_type(8)));
typedef float f32x4 __attribute__((ext_vector_type(4)));
typedef float f4 __attribute__((ext_vector_type(4)));
typedef ushort u16x4 __attribute__((ext_vector_type(4)));

#define NEG_INF (-__builtin_inff())

__device__ inline ushort f2bf(float f) {
    union { float f; uint32_t u; } c{f};
    uint32_t u = c.u;
    uint32_t r = (u + 0x7FFF + ((u >> 16) & 1)) >> 16;
    return (ushort)r;
}
// packed bf16 pair helpers: lo = element 0, hi = element 1
__device__ inline uint32_t cvt_pk_bf16(float lo, float hi) {
    uint32_t r;
    asm("v_cvt_pk_bf16_f32 %0, %1, %2" : "=v"(r) : "v"(lo), "v"(hi));
    return r;
}
__device__ inline float up0(uint32_t p) {
    union { uint32_t u; float f; } c{p << 16}; return c.f;
}
__device__ inline float up1(uint32_t p) {
    union { uint32_t u; float f; } c{p & 0xFFFF0000u}; return c.f;
}

__device__ inline float waveReduceMax(float v) {
    #pragma unroll
    for (int o = 32; o > 0; o >>= 1) v = fmaxf(v, __shfl_xor(v, o));
    return v;
}
__device__ inline float waveReduceSum(float v) {
    #pragma unroll
    for (int o = 32; o > 0; o >>= 1) v += __shfl_xor(v, o);
    return v;
}

// ---- sorting-network primitives (descending) -------------------------------
__device__ inline void CE(float& a, float& b) {
    float mx = fmaxf(a, b);
    b = fminf(a, b);
    a = mx;
}
// Batcher odd-even mergesort, 8 elements, descending, 19 comparators
__device__ inline void sort8(float (&l)[8]) {
    CE(l[0],l[1]); CE(l[2],l[3]); CE(l[4],l[5]); CE(l[6],l[7]);
    CE(l[0],l[2]); CE(l[1],l[3]); CE(l[4],l[6]); CE(l[5],l[7]);
    CE(l[1],l[2]); CE(l[5],l[6]);
    CE(l[0],l[4]); CE(l[1],l[5]); CE(l[2],l[6]); CE(l[3],l[7]);
    CE(l[2],l[4]); CE(l[3],l[5]);
    CE(l[1],l[2]); CE(l[3],l[4]); CE(l[5],l[6]);
}
// a, b sorted desc -> a = sorted desc top-8 of union (bitonic half-merge)
__device__ inline void mergeTop8(float (&a)[8], const float (&b)[8]) {
    float t[8];
    #pragma unroll
    for (int i = 0; i < 8; i++) t[i] = fmaxf(a[i], b[7 - i]);
    CE(t[0],t[4]); CE(t[1],t[5]); CE(t[2],t[6]); CE(t[3],t[7]);
    CE(t[0],t[2]); CE(t[1],t[3]); CE(t[4],t[6]); CE(t[5],t[7]);
    CE(t[0],t[1]); CE(t[2],t[3]); CE(t[4],t[5]); CE(t[6],t[7]);
    #pragma unroll
    for (int i = 0; i < 8; i++) a[i] = t[i];
}

#define GLL16(src, dst)                                                        \
    __builtin_amdgcn_global_load_lds(                                          \
        (const __attribute__((address_space(1))) void*)(src),                  \
        (__attribute__((address_space(3))) void*)(dst), 16, 0, 0)

// ---------------------------------------------------------------------------
__global__ __launch_bounds__(64) void coef_k(const float* __restrict__ alpha,
                                             const float* __restrict__ beta,
                                             float* __restrict__ coef) {
    if (threadIdx.x == 0) {
        float a0 = alpha[0], a1 = alpha[1], a2 = alpha[2];
        float m = fmaxf(a0, fmaxf(a1, a2));
        float e0 = expf(a0 - m), e1 = expf(a1 - m), e2 = expf(a2 - m);
        float s = e0 + e1 + e2;
        coef[0] = e0 / s; coef[1] = e1 / s; coef[2] = e2 / s;
        coef[3] = beta[0];
    }
}

// ---------------------------------------------------------------------------
// Fused preparation: all roles independent (transpose reads x directly).
// blocks [0,4096):       prep_x   — row normalize -> xn bf16; cast -> xb bf16
// blocks [4096,4608):    transpose x (fp32) -> xbT bf16 (512x4096)
// blocks [4608,4736):    conv+transpose W_in / W_out -> WinT / WoutT
__global__ __launch_bounds__(256) void prep_fused(
    const float* __restrict__ x, ushort* __restrict__ xn,
    ushort* __restrict__ xb, ushort* __restrict__ xbT,
    const float* __restrict__ W_in, ushort* __restrict__ WinT,
    const float* __restrict__ W_out, ushort* __restrict__ WoutT) {
    const int b = blockIdx.x;
    const int tid = threadIdx.x;
    __shared__ float b4[4];
    __shared__ ushort t[64][65];

    if (b < 4096) {
        const int row = b;
        int lane = tid & 63, w = tid >> 6;
        const float* xr = x + (size_t)row * FDIM;
        float v0 = xr[tid], v1 = xr[tid + 256];
        float ss = v0 * v0 + v1 * v1;
        ss = waveReduceSum(ss);
        if (lane == 0) b4[w] = ss;
        __syncthreads();
        float tot = b4[0] + b4[1] + b4[2] + b4[3];
        float inv = 1.f / fmaxf(sqrtf(tot), 1e-12f);
        size_t o = (size_t)row * FDIM + tid;
        xn[o] = f2bf(v0 * inv);  xn[o + 256] = f2bf(v1 * inv);
        xb[o] = f2bf(v0);        xb[o + 256] = f2bf(v1);
    } else if (b < 4608) {
        const int tb = b - 4096;
        const int c0 = (tb & 7) * 64, r0 = (tb >> 3) * 64;
        int lx = tid & 63, ly = tid >> 6;
        #pragma unroll
        for (int i = 0; i < 16; i++)
            t[ly + 4 * i][lx] = f2bf(x[(size_t)(r0 + ly + 4 * i) * FDIM + c0 + lx]);
        __syncthreads();
        #pragma unroll
        for (int i = 0; i < 16; i++)
            xbT[(size_t)(c0 + ly + 4 * i) * NROW + r0 + lx] = t[lx][ly + 4 * i];
    } else {
        const int cb = b - 4608;
        const float* Wf = (cb >> 6) ? W_out : W_in;
        ushort* WT = (cb >> 6) ? WoutT : WinT;
        const int idx = cb & 63;
        const int c0 = (idx & 7) * 64, r0 = (idx >> 3) * 64;
        int lx = tid & 63, ly = tid >> 6;
        #pragma unroll
        for (int i = 0; i < 16; i++)
            t[ly + 4 * i][lx] = f2bf(Wf[(size_t)(r0 + ly + 4 * i) * 512 + c0 + lx]);
        __syncthreads();
        #pragma unroll
        for (int i = 0; i < 16; i++)
            WT[(size_t)(c0 + ly + 4 * i) * 512 + r0 + lx] = t[lx][ly + 4 * i];
    }
}

// ---------------------------------------------------------------------------
// SYMMETRIC sim GEMM: simb = xn @ xn^T (bf16 out). Only the 528 upper-
// triangle 128x128 tiles are computed (51% of the MFMA work); off-diagonal
// tiles are written twice: normal (coalesced) + transposed via LDS staging
// (130-ushort pitch -> 2-way bank access = free; dword global stores).
__global__ __launch_bounds__(256) void gemm_sym(
    const ushort* __restrict__ A, ushort* __restrict__ C) {
    constexpr int BK = 64;
    constexpr int NT = 128 * BK;              // 8192 ushorts per operand
    __shared__ __align__(16) ushort smem[128 * 130];  // 33.3KB; As/Bs alias
    ushort* As = smem;
    ushort* Bs = smem + NT;

    // triangular block mapping: bid -> (bi, bj), bi <= bj
    int bi = 0, rem = blockIdx.x;
    while (rem >= 32 - bi) { rem -= 32 - bi; bi++; }
    const int bj = bi + rem;
    const int m0 = bi * 128, n0 = bj * 128;

    const int tid = threadIdx.x;
    const int lane = tid & 63, w = tid >> 6;
    const int wr = w >> 1, wc = w & 1;

    f32x4 acc[4][4];
    #pragma unroll
    for (int mi = 0; mi < 4; mi++)
        #pragma unroll
        for (int ni = 0; ni < 4; ni++)
            #pragma unroll
            for (int r = 0; r < 4; r++) acc[mi][ni][r] = 0.f;

    for (int k0 = 0; k0 < FDIM; k0 += BK) {
        #pragma unroll
        for (int p = 0; p < 4; ++p) {
            int chunk = p * 256 + tid;
            int row = chunk / 8;
            int kc = chunk % 8;
            GLL16(A + (size_t)(m0 + row) * FDIM + k0 + kc * 8,
                  As + (size_t)(p * 256 + w * 64) * 8);
            GLL16(A + (size_t)(n0 + row) * FDIM + k0 + kc * 8,
                  Bs + (size_t)(p * 256 + w * 64) * 8);
        }
        __syncthreads();
        #pragma unroll
        for (int kf = 0; kf < BK / 32; ++kf) {
            const int ko = kf * 32 + (lane >> 4) * 8;
            bf16x8 av[4], bv[4];
            #pragma unroll
            for (int mi = 0; mi < 4; mi++)
                av[mi] = *(const bf16x8*)&As[(wr * 64 + mi * 16 + (lane & 15)) * BK + ko];
            #pragma unroll
            for (int ni = 0; ni < 4; ni++)
                bv[ni] = *(const bf16x8*)&Bs[(wc * 64 + ni * 16 + (lane & 15)) * BK + ko];
            #pragma unroll
            for (int mi = 0; mi < 4; mi++)
                #pragma unroll
                for (int ni = 0; ni < 4; ni++)
                    acc[mi][ni] = __builtin_amdgcn_mfma_f32_16x16x32_bf16(
                        av[mi], bv[ni], acc[mi][ni], 0, 0, 0);
        }
        __syncthreads();
    }

    // normal write + LDS stage (bf16)
    #pragma unroll
    for (int mi = 0; mi < 4; mi++) {
        #pragma unroll
        for (int ni = 0; ni < 4; ni++) {
            int lcol = wc * 64 + ni * 16 + (lane & 15);
            #pragma unroll
            for (int r = 0; r < 4; r++) {
                int lrow = wr * 64 + mi * 16 + (lane >> 4) * 4 + r;
                ushort hv = f2bf(acc[mi][ni][r]);
                C[(size_t)(m0 + lrow) * NROW + n0 + lcol] = hv;
                smem[lrow * 130 + lcol] = hv;
            }
        }
    }

    if (bi != bj) {
        __syncthreads();
        // transposed write: wave wv covers rows r2 in [wv*32, wv*32+32);
        // lane covers cols c2 = lane*2, lane*2+1 -> one dword store, 256B/wave
        const int wv = w;
        #pragma unroll 4
        for (int i = 0; i < 32; i++) {
            int r2 = wv * 32 + i;
            ushort a = smem[(lane * 2) * 130 + r2];
            ushort bb = smem[(lane * 2 + 1) * 130 + r2];
            uint32_t pk = (uint32_t)a | ((uint32_t)bb << 16);
            *(uint32_t*)&C[(size_t)(n0 + r2) * NROW + m0 + lane * 2] = pk;
        }
    }
}

// ---------------------------------------------------------------------------
// C = A(MxK) * B(NxK)^T, bf16 MFMA 16x16x32, 128x128 tile, 4 waves, BK=64.
// EPI 1: fp32 C + bias[col].  EPI 3: split-K partial (z selects K-chunk 1024).
template <int EPI>
__global__ __launch_bounds__(256) void gemm_abT(
    const ushort* __restrict__ A, int lda,
    const ushort* __restrict__ B, int ldb,
    int Kdim, int ldc,
    float* __restrict__ Cf, ushort* __restrict__ Cb,
    const float* __restrict__ bias) {
    constexpr int BK = 64;
    constexpr int NT = 128 * BK;
    constexpr int CPR = BK / 8;               // 8 chunks of 16B per row
    constexpr int PASSES = (128 * CPR) / 256; // 4
    __shared__ __align__(16) ushort smem[2 * NT];
    ushort* As = smem;
    ushort* Bs = smem + NT;

    if constexpr (EPI == 3) {
        A += (size_t)blockIdx.z * 1024;
        B += (size_t)blockIdx.z * 1024;
        Cf += (size_t)blockIdx.z * ((size_t)NROW * 512);
    }

    const int tid = threadIdx.x;
    const int lane = tid & 63, w = tid >> 6;
    const int wr = w >> 1, wc = w & 1;
    const int m0 = blockIdx.y * 128;
    const int n0 = blockIdx.x * 128;

    f32x4 acc[4][4];
    #pragma unroll
    for (int mi = 0; mi < 4; mi++)
        #pragma unroll
        for (int ni = 0; ni < 4; ni++)
            #pragma unroll
            for (int r = 0; r < 4; r++) acc[mi][ni][r] = 0.f;

    for (int k0 = 0; k0 < Kdim; k0 += BK) {
        #pragma unroll
        for (int p = 0; p < PASSES; ++p) {
            int chunk = p * 256 + tid;
            int row = chunk / CPR;
            int kc = chunk % CPR;
            const ushort* asrc = A + (size_t)(m0 + row) * lda + k0 + kc * 8;
            const ushort* bsrc = B + (size_t)(n0 + row) * ldb + k0 + kc * 8;
            ushort* abase = As + (size_t)(p * 256 + w * 64) * 8;
            ushort* bbase = Bs + (size_t)(p * 256 + w * 64) * 8;
            GLL16(asrc, abase);
            GLL16(bsrc, bbase);
        }
        __syncthreads();
        #pragma unroll
        for (int kf = 0; kf < BK / 32; ++kf) {
            const int ko = kf * 32 + (lane >> 4) * 8;
            bf16x8 av[4], bv[4];
            #pragma unroll
            for (int mi = 0; mi < 4; mi++)
                av[mi] = *(const bf16x8*)&As[(wr * 64 + mi * 16 + (lane & 15)) * BK + ko];
            #pragma unroll
            for (int ni = 0; ni < 4; ni++)
                bv[ni] = *(const bf16x8*)&Bs[(wc * 64 + ni * 16 + (lane & 15)) * BK + ko];
            #pragma unroll
            for (int mi = 0; mi < 4; mi++)
                #pragma unroll
                for (int ni = 0; ni < 4; ni++)
                    acc[mi][ni] = __builtin_amdgcn_mfma_f32_16x16x32_bf16(
                        av[mi], bv[ni], acc[mi][ni], 0, 0, 0);
        }
        __syncthreads();
    }

    #pragma unroll
    for (int mi = 0; mi < 4; mi++) {
        #pragma unroll
        for (int ni = 0; ni < 4; ni++) {
            int col = n0 + wc * 64 + ni * 16 + (lane & 15);
            #pragma unroll
            for (int r = 0; r < 4; r++) {
                int rowg = m0 + wr * 64 + mi * 16 + (lane >> 4) * 4 + r;
                size_t off = (size_t)rowg * ldc + col;
                float v = acc[mi][ni][r];
                if constexpr (EPI == 1) {
                    Cf[off] = v + bias[col];
                } else {
                    Cf[off] = v;
                }
            }
        }
    }
}

// ---------------------------------------------------------------------------
// topk + build M.  One row per 256-thread block; wave w owns cols
// [w*1024, (w+1)*1024); lane owns 16 cols: j = w*1024 + q*256 + lane*4 + e.
// Structure = r5 (best known: VGPR 60, no spill).  NEW: #pragma unroll 1 on
// the hop loop — the fully-unrolled 3-hop body (~25-30KB: sort networks +
// 6-level shuffle trees x3) is near the 32KB shared L1I; I-fetch misses
// would stall all waves uniformly, matching the structure-insensitive
// 131-148us plateau of r3/r5/r6/r7/r8.  This cuts code ~3x.
// Spill tripwire: WRITE_SIZE must stay 32768 KB (r4 lesson).
__global__ __launch_bounds__(256) void topk_build_M(
    const ushort* __restrict__ simb, const float* __restrict__ adj,
    const float* __restrict__ rmask, const float* __restrict__ coef,
    ushort* __restrict__ Mout) {
    const int tid = threadIdx.x;
    const int lane = tid & 63;
    const int w = tid >> 6;
    const int row = blockIdx.x;
    __shared__ float wl[3][4][8];

    const int cbase = w * 1024 + lane * 4;
    const size_t hopstride = (size_t)NROW * NROW;

    const ushort* srow = simb + (size_t)row * NROW + cbase;
    const float* arow = adj + (size_t)row * NROW + cbase;
    const float* rrow = rmask + (size_t)row * NROW + cbase;

    uint2 svp[4];
    #pragma unroll
    for (int q = 0; q < 4; q++)
        svp[q] = *(const uint2*)(srow + q * 256);

    float macc[4][4];
    #pragma unroll
    for (int q = 0; q < 4; q++)
        #pragma unroll
        for (int c = 0; c < 4; c++) macc[q][c] = 0.f;

    #pragma unroll 1
    for (int k = 0; k < 3; ++k) {
        const float* ar = arow + (size_t)k * hopstride;
        const float* rr = rrow + (size_t)k * hopstride;

        // batch-issue: rmask first (consumed first), adj behind it
        f4 rv[4], a[4];
        #pragma unroll
        for (int q = 0; q < 4; q++) rv[q] = *(const f4*)(rr + q * 256);
        #pragma unroll
        for (int q = 0; q < 4; q++) a[q] = *(const f4*)(ar + q * 256);

        uint32_t rbits = 0;
        #pragma unroll
        for (int q = 0; q < 4; q++) {
            rbits |= (rv[q].x < 0.5f ? 1u : 0u) << (q * 4 + 0);
            rbits |= (rv[q].y < 0.5f ? 1u : 0u) << (q * 4 + 1);
            rbits |= (rv[q].z < 0.5f ? 1u : 0u) << (q * 4 + 2);
            rbits |= (rv[q].w < 0.5f ? 1u : 0u) << (q * 4 + 3);
        }

        uint2 avp[4];
        #pragma unroll
        for (int q = 0; q < 4; q++) {
            avp[q].x = cvt_pk_bf16(a[q].x, a[q].y);
            avp[q].y = cvt_pk_bf16(a[q].z, a[q].w);
        }

        // per-lane top-8 of 16 rounded products
        float lo8[8], hi8[8];
        #pragma unroll
        for (int qq = 0; qq < 2; qq++) {
            lo8[qq * 4 + 0] = up0(avp[qq].x) * up0(svp[qq].x);
            lo8[qq * 4 + 1] = up1(avp[qq].x) * up1(svp[qq].x);
            lo8[qq * 4 + 2] = up0(avp[qq].y) * up0(svp[qq].y);
            lo8[qq * 4 + 3] = up1(avp[qq].y) * up1(svp[qq].y);
        }
        #pragma unroll
        for (int qq = 0; qq < 2; qq++) {
            const int q = 2 + qq;
            hi8[qq * 4 + 0] = up0(avp[q].x) * up0(svp[q].x);
            hi8[qq * 4 + 1] = up1(avp[q].x) * up1(svp[q].x);
            hi8[qq * 4 + 2] = up0(avp[q].y) * up0(svp[q].y);
            hi8[qq * 4 + 3] = up1(avp[q].y) * up1(svp[q].y);
        }
        sort8(lo8);
        sort8(hi8);
        mergeTop8(lo8, hi8);

        // wave top-8: 6-level merge tree
        #pragma unroll
        for (int lvl = 0; lvl < 6; lvl++) {
            float b[8];
            #pragma unroll
            for (int i = 0; i < 8; i++) b[i] = __shfl_xor(lo8[i], 1 << lvl);
            mergeTop8(lo8, b);
        }

        if (lane < 8) wl[k][w][lane] = lo8[lane];
        __syncthreads();
        #pragma unroll
        for (int ww = 0; ww < 4; ww++) {
            if (ww != w) {
                float b[8];
                #pragma unroll
                for (int i = 0; i < 8; i++) b[i] = wl[k][ww][i];
                mergeTop8(lo8, b);
            }
        }
        const float thr = lo8[7];

        const float ak = coef[k];
        const float aksq = ak * ak;
        #pragma unroll
        for (int q = 0; q < 4; q++) {
            float av0 = up0(avp[q].x), av1 = up1(avp[q].x);
            float av2 = up0(avp[q].y), av3 = up1(avp[q].y);
            float s0 = up0(svp[q].x), s1 = up1(svp[q].x);
            float s2 = up0(svp[q].y), s3 = up1(svp[q].y);
            bool m0 = ((rbits >> (q * 4 + 0)) & 1) || (av0 * s0 >= thr);
            bool m1 = ((rbits >> (q * 4 + 1)) & 1) || (av1 * s1 >= thr);
            bool m2 = ((rbits >> (q * 4 + 2)) & 1) || (av2 * s2 >= thr);
            bool m3 = ((rbits >> (q * 4 + 3)) & 1) || (av3 * s3 >= thr);
            macc[q][0] += m0 ? aksq * av0 : 0.f;
            macc[q][1] += m1 ? aksq * av1 : 0.f;
            macc[q][2] += m2 ? aksq * av2 : 0.f;
            macc[q][3] += m3 ? aksq * av3 : 0.f;
        }
        __syncthreads();
    }

    ushort* mrow = Mout + (size_t)row * NROW + cbase;
    #pragma unroll
    for (int q = 0; q < 4; q++) {
        u16x4 o;
        o[0] = f2bf(up0(svp[q].x) * macc[q][0]);
        o[1] = f2bf(up1(svp[q].x) * macc[q][1]);
        o[2] = f2bf(up0(svp[q].y) * macc[q][2]);
        o[3] = f2bf(up1(svp[q].y) * macc[q][3]);
        *(u16x4*)(mrow + q * 256) = o;
    }
}

// ---------------------------------------------------------------------------
// H = relu(cb*Hlow + (1-cb)*sum_z parts[z]) -> bf16
__global__ __launch_bounds__(256) void reduce_relu(
    const float* __restrict__ parts, const float* __restrict__ hlow,
    const float* __restrict__ coef, ushort* __restrict__ Hb) {
    const size_t i = (size_t)blockIdx.x * 256 + threadIdx.x;  // f4 index
    const f4* p4 = (const f4*)parts;
    f4 s = p4[i];
    #pragma unroll
    for (int z = 1; z < 4; z++) s += p4[(size_t)z * 524288 + i];
    f4 hl = ((const f4*)hlow)[i];
    float cb = coef[3];
    u16x4 o;
    #pragma unroll
    for (int c = 0; c < 4; c++) {
        float h = cb * hl[c] + (1.f - cb) * s[c];
        o[c] = f2bf(fmaxf(h, 0.f));
    }
    *((u16x4*)Hb + i) = o;
}

// ---------------------------------------------------------------------------
__global__ __launch_bounds__(256) void logsoftmax_k(const float* __restrict__ L,
                                                    float* __restrict__ out) {
    int row = blockIdx.x, tid = threadIdx.x;
    int lane = tid & 63, w = tid >> 6;
    const float* lr = L + (size_t)row * 512;
    float v0 = lr[tid], v1 = lr[tid + 256];
    __shared__ float bm[4], bs[4];
    float m = fmaxf(v0, v1);
    m = waveReduceMax(m);
    if (lane == 0) bm[w] = m;
    __syncthreads();
    float M = fmaxf(fmaxf(bm[0], bm[1]), fmaxf(bm[2], bm[3]));
    float s = expf(v0 - M) + expf(v1 - M);
    s = waveReduceSum(s);
    if (lane == 0) bs[w] = s;
    __syncthreads();
    float S = bs[0] + bs[1] + bs[2] + bs[3];
    float lse = M + logf(S);
    float* orow = out + (size_t)row * 512;
    orow[tid] = v0 - lse;
    orow[tid + 256] = v1 - lse;
}

// ---------------------------------------------------------------------------
extern "C" void kernel_launch(void* const* d_in, const int* in_sizes, int n_in,
                              void* d_out, int out_size, void* d_ws, size_t ws_size,
                              hipStream_t stream) {
    const float* x     = (const float*)d_in[0];
    const float* adj   = (const float*)d_in[1];
    const float* rmask = (const float*)d_in[2];
    const float* W_in  = (const float*)d_in[3];
    const float* b_in  = (const float*)d_in[4];
    const float* W_out = (const float*)d_in[5];
    const float* b_out = (const float*)d_in[6];
    const float* alpha = (const float*)d_in[7];
    const float* beta  = (const float*)d_in[8];
    float* out = (float*)d_out;

    const size_t MB = 1024 * 1024;
    char* wsb = (char*)d_ws;
    // [0,32):  simb bf16 -> (dead after topk) -> parts fp32 4x8MB -> logits [0,8)
    // [32,64): Mb bf16
    // [64,68): xn bf16    [68,72): xb bf16    [72,76): xbT bf16
    // [76,76.5): WinT     [76.5,77): WoutT
    // [77,85): Hlow fp32  [85,89): Hb bf16    [89): coef
    ushort* simb   = (ushort*)wsb;
    float*  parts  = (float*)wsb;
    float*  logits = (float*)wsb;
    ushort* Mb     = (ushort*)(wsb + 32 * MB);
    ushort* xn     = (ushort*)(wsb + 64 * MB);
    ushort* xb     = (ushort*)(wsb + 68 * MB);
    ushort* xbT    = (ushort*)(wsb + 72 * MB);
    ushort* WinT   = (ushort*)(wsb + 76 * MB);
    ushort* WoutT  = (ushort*)(wsb + 76 * MB + 512 * 1024);
    float*  Hlow   = (float*)(wsb + 77 * MB);
    ushort* Hb     = (ushort*)(wsb + 85 * MB);
    float*  coef   = (float*)(wsb + 89 * MB);

    coef_k<<<1, 64, 0, stream>>>(alpha, beta, coef);

    // fused prep: xn/xb + x^T + both weight transposes (all independent)
    prep_fused<<<4096 + 512 + 128, 256, 0, stream>>>(
        x, xn, xb, xbT, W_in, WinT, W_out, WoutT);

    // sim = xn @ xn^T -> bf16 (symmetric: 528 upper-triangle tiles)
    gemm_sym<<<528, 256, 0, stream>>>(xn, simb);

    // combined masked adjacency M (bf16)
    topk_build_M<<<NROW, 256, 0, stream>>>(simb, adj, rmask, coef, Mb);

    // H_low = x @ W_in + b_in
    gemm_abT<1><<<dim3(4, 32), 256, 0, stream>>>(
        xb, FDIM, WinT, FDIM, FDIM, 512, Hlow, nullptr, b_in);

    // split-K=4: parts[z] = M[:, z*1024:+1024] @ x[z*1024:+1024, :]
    gemm_abT<3><<<dim3(4, 32, 4), 256, 0, stream>>>(
        Mb, NROW, xbT, NROW, 1024, 512, parts, nullptr, nullptr);

    // H = relu(b*Hlow + (1-b)*sum parts) -> bf16
    reduce_relu<<<2048, 256, 0, stream>>>(parts, Hlow, coef, Hb);

    // logits = H @ W_out + b_out
    gemm_abT<1><<<dim3(4, 32), 256, 0, stream>>>(
        Hb, 512, WoutT, 512, 512, 512, logits, nullptr, b_out);

    logsoftmax_k<<<NROW, 256, 0, stream>>>(logits, out);
}

// Round 10
// 210.021 us; speedup vs baseline: 1.1532x; 1.0168x over previous
//
#include <hip/hip_runtime.h>
#include <hip/hip_bf16.h>
#include <stdint.h>

#define NROW 4096
#define FDIM 512

typedef short bf16x8 __attribute__((ext_vector_type(8)));
typedef float f32x4 __attribute__((ext_vector_type(4)));
typedef float f4 __attribute__((ext_vector_type(4)));
typedef ushort u16x4 __attribute__((ext_vector_type(4)));

#define NEG_INF (-__builtin_inff())

__device__ inline ushort f2bf(float f) {
    union { float f; uint32_t u; } c{f};
    uint32_t u = c.u;
    uint32_t r = (u + 0x7FFF + ((u >> 16) & 1)) >> 16;
    return (ushort)r;
}
// packed bf16 pair helpers: lo = element 0, hi = element 1
__device__ inline uint32_t cvt_pk_bf16(float lo, float hi) {
    uint32_t r;
    asm("v_cvt_pk_bf16_f32 %0, %1, %2" : "=v"(r) : "v"(lo), "v"(hi));
    return r;
}
__device__ inline float up0(uint32_t p) {
    union { uint32_t u; float f; } c{p << 16}; return c.f;
}
__device__ inline float up1(uint32_t p) {
    union { uint32_t u; float f; } c{p & 0xFFFF0000u}; return c.f;
}

__device__ inline float waveReduceMax(float v) {
    #pragma unroll
    for (int o = 32; o > 0; o >>= 1) v = fmaxf(v, __shfl_xor(v, o));
    return v;
}
__device__ inline float waveReduceSum(float v) {
    #pragma unroll
    for (int o = 32; o > 0; o >>= 1) v += __shfl_xor(v, o);
    return v;
}

// ---- sorting-network primitives (descending) -------------------------------
__device__ inline void CE(float& a, float& b) {
    float mx = fmaxf(a, b);
    b = fminf(a, b);
    a = mx;
}
// Batcher odd-even mergesort, 8 elements, descending, 19 comparators
__device__ inline void sort8(float (&l)[8]) {
    CE(l[0],l[1]); CE(l[2],l[3]); CE(l[4],l[5]); CE(l[6],l[7]);
    CE(l[0],l[2]); CE(l[1],l[3]); CE(l[4],l[6]); CE(l[5],l[7]);
    CE(l[1],l[2]); CE(l[5],l[6]);
    CE(l[0],l[4]); CE(l[1],l[5]); CE(l[2],l[6]); CE(l[3],l[7]);
    CE(l[2],l[4]); CE(l[3],l[5]);
    CE(l[1],l[2]); CE(l[3],l[4]); CE(l[5],l[6]);
}
// a, b sorted desc -> a = sorted desc top-8 of union (bitonic half-merge)
__device__ inline void mergeTop8(float (&a)[8], const float (&b)[8]) {
    float t[8];
    #pragma unroll
    for (int i = 0; i < 8; i++) t[i] = fmaxf(a[i], b[7 - i]);
    CE(t[0],t[4]); CE(t[1],t[5]); CE(t[2],t[6]); CE(t[3],t[7]);
    CE(t[0],t[2]); CE(t[1],t[3]); CE(t[4],t[6]); CE(t[5],t[7]);
    CE(t[0],t[1]); CE(t[2],t[3]); CE(t[4],t[5]); CE(t[6],t[7]);
    #pragma unroll
    for (int i = 0; i < 8; i++) a[i] = t[i];
}
// 8th-largest of union of two sorted-8 lists: min of the bitonic half-merge
// stage (classic half-cleaner: {max(a[i],b[7-i])} IS the top-8 multiset).
__device__ inline float merge8th(const float (&a)[8], const float (&b)[8]) {
    float t0 = fminf(fmaxf(a[0], b[7]), fmaxf(a[1], b[6]));
    float t1 = fminf(fmaxf(a[2], b[5]), fmaxf(a[3], b[4]));
    float t2 = fminf(fmaxf(a[4], b[3]), fmaxf(a[5], b[2]));
    float t3 = fminf(fmaxf(a[6], b[1]), fmaxf(a[7], b[0]));
    return fminf(fminf(t0, t1), fminf(t2, t3));
}

#define GLL16(src, dst)                                                        \
    __builtin_amdgcn_global_load_lds(                                          \
        (const __attribute__((address_space(1))) void*)(src),                  \
        (__attribute__((address_space(3))) void*)(dst), 16, 0, 0)

// ---------------------------------------------------------------------------
__global__ __launch_bounds__(64) void coef_k(const float* __restrict__ alpha,
                                             const float* __restrict__ beta,
                                             float* __restrict__ coef) {
    if (threadIdx.x == 0) {
        float a0 = alpha[0], a1 = alpha[1], a2 = alpha[2];
        float m = fmaxf(a0, fmaxf(a1, a2));
        float e0 = expf(a0 - m), e1 = expf(a1 - m), e2 = expf(a2 - m);
        float s = e0 + e1 + e2;
        coef[0] = e0 / s; coef[1] = e1 / s; coef[2] = e2 / s;
        coef[3] = beta[0];
    }
}

// ---------------------------------------------------------------------------
// Fused preparation: all roles independent (transpose reads x directly).
// blocks [0,4096):       prep_x   — row normalize -> xn bf16; cast -> xb bf16
// blocks [4096,4608):    transpose x (fp32) -> xbT bf16 (512x4096)
// blocks [4608,4736):    conv+transpose W_in / W_out -> WinT / WoutT
__global__ __launch_bounds__(256) void prep_fused(
    const float* __restrict__ x, ushort* __restrict__ xn,
    ushort* __restrict__ xb, ushort* __restrict__ xbT,
    const float* __restrict__ W_in, ushort* __restrict__ WinT,
    const float* __restrict__ W_out, ushort* __restrict__ WoutT) {
    const int b = blockIdx.x;
    const int tid = threadIdx.x;
    __shared__ float b4[4];
    __shared__ ushort t[64][65];

    if (b < 4096) {
        const int row = b;
        int lane = tid & 63, w = tid >> 6;
        const float* xr = x + (size_t)row * FDIM;
        float v0 = xr[tid], v1 = xr[tid + 256];
        float ss = v0 * v0 + v1 * v1;
        ss = waveReduceSum(ss);
        if (lane == 0) b4[w] = ss;
        __syncthreads();
        float tot = b4[0] + b4[1] + b4[2] + b4[3];
        float inv = 1.f / fmaxf(sqrtf(tot), 1e-12f);
        size_t o = (size_t)row * FDIM + tid;
        xn[o] = f2bf(v0 * inv);  xn[o + 256] = f2bf(v1 * inv);
        xb[o] = f2bf(v0);        xb[o + 256] = f2bf(v1);
    } else if (b < 4608) {
        const int tb = b - 4096;
        const int c0 = (tb & 7) * 64, r0 = (tb >> 3) * 64;
        int lx = tid & 63, ly = tid >> 6;
        #pragma unroll
        for (int i = 0; i < 16; i++)
            t[ly + 4 * i][lx] = f2bf(x[(size_t)(r0 + ly + 4 * i) * FDIM + c0 + lx]);
        __syncthreads();
        #pragma unroll
        for (int i = 0; i < 16; i++)
            xbT[(size_t)(c0 + ly + 4 * i) * NROW + r0 + lx] = t[lx][ly + 4 * i];
    } else {
        const int cb = b - 4608;
        const float* Wf = (cb >> 6) ? W_out : W_in;
        ushort* WT = (cb >> 6) ? WoutT : WinT;
        const int idx = cb & 63;
        const int c0 = (idx & 7) * 64, r0 = (idx >> 3) * 64;
        int lx = tid & 63, ly = tid >> 6;
        #pragma unroll
        for (int i = 0; i < 16; i++)
            t[ly + 4 * i][lx] = f2bf(Wf[(size_t)(r0 + ly + 4 * i) * 512 + c0 + lx]);
        __syncthreads();
        #pragma unroll
        for (int i = 0; i < 16; i++)
            WT[(size_t)(c0 + ly + 4 * i) * 512 + r0 + lx] = t[lx][ly + 4 * i];
    }
}

// ---------------------------------------------------------------------------
// SYMMETRIC sim GEMM: simb = xn @ xn^T (bf16 out). Only the 528 upper-
// triangle 128x128 tiles are computed; off-diagonal tiles are written twice:
// normal (coalesced) + transposed via LDS staging.
__global__ __launch_bounds__(256) void gemm_sym(
    const ushort* __restrict__ A, ushort* __restrict__ C) {
    constexpr int BK = 64;
    constexpr int NT = 128 * BK;
    __shared__ __align__(16) ushort smem[128 * 130];
    ushort* As = smem;
    ushort* Bs = smem + NT;

    int bi = 0, rem = blockIdx.x;
    while (rem >= 32 - bi) { rem -= 32 - bi; bi++; }
    const int bj = bi + rem;
    const int m0 = bi * 128, n0 = bj * 128;

    const int tid = threadIdx.x;
    const int lane = tid & 63, w = tid >> 6;
    const int wr = w >> 1, wc = w & 1;

    f32x4 acc[4][4];
    #pragma unroll
    for (int mi = 0; mi < 4; mi++)
        #pragma unroll
        for (int ni = 0; ni < 4; ni++)
            #pragma unroll
            for (int r = 0; r < 4; r++) acc[mi][ni][r] = 0.f;

    for (int k0 = 0; k0 < FDIM; k0 += BK) {
        #pragma unroll
        for (int p = 0; p < 4; ++p) {
            int chunk = p * 256 + tid;
            int row = chunk / 8;
            int kc = chunk % 8;
            GLL16(A + (size_t)(m0 + row) * FDIM + k0 + kc * 8,
                  As + (size_t)(p * 256 + w * 64) * 8);
            GLL16(A + (size_t)(n0 + row) * FDIM + k0 + kc * 8,
                  Bs + (size_t)(p * 256 + w * 64) * 8);
        }
        __syncthreads();
        #pragma unroll
        for (int kf = 0; kf < BK / 32; ++kf) {
            const int ko = kf * 32 + (lane >> 4) * 8;
            bf16x8 av[4], bv[4];
            #pragma unroll
            for (int mi = 0; mi < 4; mi++)
                av[mi] = *(const bf16x8*)&As[(wr * 64 + mi * 16 + (lane & 15)) * BK + ko];
            #pragma unroll
            for (int ni = 0; ni < 4; ni++)
                bv[ni] = *(const bf16x8*)&Bs[(wc * 64 + ni * 16 + (lane & 15)) * BK + ko];
            #pragma unroll
            for (int mi = 0; mi < 4; mi++)
                #pragma unroll
                for (int ni = 0; ni < 4; ni++)
                    acc[mi][ni] = __builtin_amdgcn_mfma_f32_16x16x32_bf16(
                        av[mi], bv[ni], acc[mi][ni], 0, 0, 0);
        }
        __syncthreads();
    }

    #pragma unroll
    for (int mi = 0; mi < 4; mi++) {
        #pragma unroll
        for (int ni = 0; ni < 4; ni++) {
            int lcol = wc * 64 + ni * 16 + (lane & 15);
            #pragma unroll
            for (int r = 0; r < 4; r++) {
                int lrow = wr * 64 + mi * 16 + (lane >> 4) * 4 + r;
                ushort hv = f2bf(acc[mi][ni][r]);
                C[(size_t)(m0 + lrow) * NROW + n0 + lcol] = hv;
                smem[lrow * 130 + lcol] = hv;
            }
        }
    }

    if (bi != bj) {
        __syncthreads();
        const int wv = w;
        #pragma unroll 4
        for (int i = 0; i < 32; i++) {
            int r2 = wv * 32 + i;
            ushort a = smem[(lane * 2) * 130 + r2];
            ushort bb = smem[(lane * 2 + 1) * 130 + r2];
            uint32_t pk = (uint32_t)a | ((uint32_t)bb << 16);
            *(uint32_t*)&C[(size_t)(n0 + r2) * NROW + m0 + lane * 2] = pk;
        }
    }
}

// ---------------------------------------------------------------------------
// C = A(MxK) * B(NxK)^T, bf16 MFMA 16x16x32, 128x128 tile, 4 waves, BK=64.
// EPI 1: fp32 C + bias[col].
// EPI 3: split-K partials. z<4: K-chunk 1024 of M@x into parts[z].
//        z==4: H_low = A2(xb) @ B2(WinT)^T (K=512, no bias) into Cf4.
template <int EPI>
__global__ __launch_bounds__(256) void gemm_abT(
    const ushort* __restrict__ A, int lda,
    const ushort* __restrict__ B, int ldb,
    int Kdim, int ldc,
    float* __restrict__ Cf, ushort* __restrict__ Cb,
    const float* __restrict__ bias,
    const ushort* __restrict__ A2, const ushort* __restrict__ B2,
    float* __restrict__ Cf4) {
    constexpr int BK = 64;
    constexpr int NT = 128 * BK;
    constexpr int CPR = BK / 8;
    constexpr int PASSES = (128 * CPR) / 256;
    __shared__ __align__(16) ushort smem[2 * NT];
    ushort* As = smem;
    ushort* Bs = smem + NT;

    int Kd = Kdim;
    if constexpr (EPI == 3) {
        if (blockIdx.z == 4) {
            A = A2; lda = FDIM; B = B2; ldb = FDIM; Kd = FDIM;
            Cf = Cf4;
        } else {
            A += (size_t)blockIdx.z * 1024;
            B += (size_t)blockIdx.z * 1024;
            Cf += (size_t)blockIdx.z * ((size_t)NROW * 512);
        }
    }

    const int tid = threadIdx.x;
    const int lane = tid & 63, w = tid >> 6;
    const int wr = w >> 1, wc = w & 1;
    const int m0 = blockIdx.y * 128;
    const int n0 = blockIdx.x * 128;

    f32x4 acc[4][4];
    #pragma unroll
    for (int mi = 0; mi < 4; mi++)
        #pragma unroll
        for (int ni = 0; ni < 4; ni++)
            #pragma unroll
            for (int r = 0; r < 4; r++) acc[mi][ni][r] = 0.f;

    for (int k0 = 0; k0 < Kd; k0 += BK) {
        #pragma unroll
        for (int p = 0; p < PASSES; ++p) {
            int chunk = p * 256 + tid;
            int row = chunk / CPR;
            int kc = chunk % CPR;
            const ushort* asrc = A + (size_t)(m0 + row) * lda + k0 + kc * 8;
            const ushort* bsrc = B + (size_t)(n0 + row) * ldb + k0 + kc * 8;
            ushort* abase = As + (size_t)(p * 256 + w * 64) * 8;
            ushort* bbase = Bs + (size_t)(p * 256 + w * 64) * 8;
            GLL16(asrc, abase);
            GLL16(bsrc, bbase);
        }
        __syncthreads();
        #pragma unroll
        for (int kf = 0; kf < BK / 32; ++kf) {
            const int ko = kf * 32 + (lane >> 4) * 8;
            bf16x8 av[4], bv[4];
            #pragma unroll
            for (int mi = 0; mi < 4; mi++)
                av[mi] = *(const bf16x8*)&As[(wr * 64 + mi * 16 + (lane & 15)) * BK + ko];
            #pragma unroll
            for (int ni = 0; ni < 4; ni++)
                bv[ni] = *(const bf16x8*)&Bs[(wc * 64 + ni * 16 + (lane & 15)) * BK + ko];
            #pragma unroll
            for (int mi = 0; mi < 4; mi++)
                #pragma unroll
                for (int ni = 0; ni < 4; ni++)
                    acc[mi][ni] = __builtin_amdgcn_mfma_f32_16x16x32_bf16(
                        av[mi], bv[ni], acc[mi][ni], 0, 0, 0);
        }
        __syncthreads();
    }

    #pragma unroll
    for (int mi = 0; mi < 4; mi++) {
        #pragma unroll
        for (int ni = 0; ni < 4; ni++) {
            int col = n0 + wc * 64 + ni * 16 + (lane & 15);
            #pragma unroll
            for (int r = 0; r < 4; r++) {
                int rowg = m0 + wr * 64 + mi * 16 + (lane >> 4) * 4 + r;
                size_t off = (size_t)rowg * ldc + col;
                float v = acc[mi][ni][r];
                if constexpr (EPI == 1) {
                    Cf[off] = v + bias[col];
                } else {
                    Cf[off] = v;
                }
            }
        }
    }
}

// ---------------------------------------------------------------------------
// topk + build M.  512-thread blocks = 8 waves = 2 INDEPENDENT rows
// (rloc = w>>2), 4 waves per row (wv = w&3 owns cols [wv*1024,(wv+1)*1024)),
// lane owns 16 cols.  Per-wave program identical to r9 (VGPR 60, no spill).
// WHY 512: r3-r9 all plateau ~134us with occupancy ~3 BLOCKS/CU despite
// VGPR allowing 8 waves/SIMD — testing whether the hidden limiter is
// workgroup-level residency (8 waves/block -> 2x resident waves if so).
// merge8th: final cross-wave merge only needs the 8th value -> min-of-
// bitonic-half (15 ops vs 32).
// Spill tripwire: WRITE_SIZE must stay 32768 KB (r4 lesson).
__global__ __launch_bounds__(512) void topk_build_M(
    const ushort* __restrict__ simb, const float* __restrict__ adj,
    const float* __restrict__ rmask, const float* __restrict__ coef,
    ushort* __restrict__ Mout) {
    const int tid = threadIdx.x;
    const int lane = tid & 63;
    const int w = tid >> 6;
    const int rloc = w >> 2;
    const int wv = w & 3;
    const int row = blockIdx.x * 2 + rloc;
    __shared__ float wl[2][3][4][8];

    const int cbase = wv * 1024 + lane * 4;
    const size_t hopstride = (size_t)NROW * NROW;

    const ushort* srow = simb + (size_t)row * NROW + cbase;
    const float* arow = adj + (size_t)row * NROW + cbase;
    const float* rrow = rmask + (size_t)row * NROW + cbase;

    uint2 svp[4];
    #pragma unroll
    for (int q = 0; q < 4; q++)
        svp[q] = *(const uint2*)(srow + q * 256);

    float macc[4][4];
    #pragma unroll
    for (int q = 0; q < 4; q++)
        #pragma unroll
        for (int c = 0; c < 4; c++) macc[q][c] = 0.f;

    #pragma unroll 1
    for (int k = 0; k < 3; ++k) {
        const float* ar = arow + (size_t)k * hopstride;
        const float* rr = rrow + (size_t)k * hopstride;

        f4 rv[4], a[4];
        #pragma unroll
        for (int q = 0; q < 4; q++) rv[q] = *(const f4*)(rr + q * 256);
        #pragma unroll
        for (int q = 0; q < 4; q++) a[q] = *(const f4*)(ar + q * 256);

        uint32_t rbits = 0;
        #pragma unroll
        for (int q = 0; q < 4; q++) {
            rbits |= (rv[q].x < 0.5f ? 1u : 0u) << (q * 4 + 0);
            rbits |= (rv[q].y < 0.5f ? 1u : 0u) << (q * 4 + 1);
            rbits |= (rv[q].z < 0.5f ? 1u : 0u) << (q * 4 + 2);
            rbits |= (rv[q].w < 0.5f ? 1u : 0u) << (q * 4 + 3);
        }

        uint2 avp[4];
        #pragma unroll
        for (int q = 0; q < 4; q++) {
            avp[q].x = cvt_pk_bf16(a[q].x, a[q].y);
            avp[q].y = cvt_pk_bf16(a[q].z, a[q].w);
        }

        float lo8[8], hi8[8];
        #pragma unroll
        for (int qq = 0; qq < 2; qq++) {
            lo8[qq * 4 + 0] = up0(avp[qq].x) * up0(svp[qq].x);
            lo8[qq * 4 + 1] = up1(avp[qq].x) * up1(svp[qq].x);
            lo8[qq * 4 + 2] = up0(avp[qq].y) * up0(svp[qq].y);
            lo8[qq * 4 + 3] = up1(avp[qq].y) * up1(svp[qq].y);
        }
        #pragma unroll
        for (int qq = 0; qq < 2; qq++) {
            const int q = 2 + qq;
            hi8[qq * 4 + 0] = up0(avp[q].x) * up0(svp[q].x);
            hi8[qq * 4 + 1] = up1(avp[q].x) * up1(svp[q].x);
            hi8[qq * 4 + 2] = up0(avp[q].y) * up0(svp[q].y);
            hi8[qq * 4 + 3] = up1(avp[q].y) * up1(svp[q].y);
        }
        sort8(lo8);
        sort8(hi8);
        mergeTop8(lo8, hi8);

        // wave top-8: 6-level merge tree
        #pragma unroll
        for (int lvl = 0; lvl < 6; lvl++) {
            float b[8];
            #pragma unroll
            for (int i = 0; i < 8; i++) b[i] = __shfl_xor(lo8[i], 1 << lvl);
            mergeTop8(lo8, b);
        }

        if (lane < 8) wl[rloc][k][wv][lane] = lo8[lane];
        __syncthreads();
        // merge other 3 waves' lists: 2 full merges + final min-of-bitonic
        float b0[8], b1[8], b2[8];
        const int o0 = (wv + 1) & 3, o1 = (wv + 2) & 3, o2 = (wv + 3) & 3;
        #pragma unroll
        for (int i = 0; i < 8; i++) b0[i] = wl[rloc][k][o0][i];
        #pragma unroll
        for (int i = 0; i < 8; i++) b1[i] = wl[rloc][k][o1][i];
        #pragma unroll
        for (int i = 0; i < 8; i++) b2[i] = wl[rloc][k][o2][i];
        mergeTop8(lo8, b0);
        mergeTop8(lo8, b1);
        const float thr = merge8th(lo8, b2);

        const float ak = coef[k];
        const float aksq = ak * ak;
        #pragma unroll
        for (int q = 0; q < 4; q++) {
            float av0 = up0(avp[q].x), av1 = up1(avp[q].x);
            float av2 = up0(avp[q].y), av3 = up1(avp[q].y);
            float s0 = up0(svp[q].x), s1 = up1(svp[q].x);
            float s2 = up0(svp[q].y), s3 = up1(svp[q].y);
            bool m0 = ((rbits >> (q * 4 + 0)) & 1) || (av0 * s0 >= thr);
            bool m1 = ((rbits >> (q * 4 + 1)) & 1) || (av1 * s1 >= thr);
            bool m2 = ((rbits >> (q * 4 + 2)) & 1) || (av2 * s2 >= thr);
            bool m3 = ((rbits >> (q * 4 + 3)) & 1) || (av3 * s3 >= thr);
            macc[q][0] += m0 ? aksq * av0 : 0.f;
            macc[q][1] += m1 ? aksq * av1 : 0.f;
            macc[q][2] += m2 ? aksq * av2 : 0.f;
            macc[q][3] += m3 ? aksq * av3 : 0.f;
        }
        __syncthreads();
    }

    ushort* mrow = Mout + (size_t)row * NROW + cbase;
    #pragma unroll
    for (int q = 0; q < 4; q++) {
        u16x4 o;
        o[0] = f2bf(up0(svp[q].x) * macc[q][0]);
        o[1] = f2bf(up1(svp[q].x) * macc[q][1]);
        o[2] = f2bf(up0(svp[q].y) * macc[q][2]);
        o[3] = f2bf(up1(svp[q].y) * macc[q][3]);
        *(u16x4*)(mrow + q * 256) = o;
    }
}

// ---------------------------------------------------------------------------
// H = relu(cb*(parts4 + bias) + (1-cb)*sum_{z<4} parts[z]) -> bf16
__global__ __launch_bounds__(256) void reduce_relu(
    const float* __restrict__ parts, const float* __restrict__ parts4,
    const float* __restrict__ bias, const float* __restrict__ coef,
    ushort* __restrict__ Hb) {
    const size_t i = (size_t)blockIdx.x * 256 + threadIdx.x;  // f4 index
    const f4* p4 = (const f4*)parts;
    f4 s = p4[i];
    #pragma unroll
    for (int z = 1; z < 4; z++) s += p4[(size_t)z * 524288 + i];
    f4 hl = ((const f4*)parts4)[i] + ((const f4*)bias)[i & 127];
    float cb = coef[3];
    u16x4 o;
    #pragma unroll
    for (int c = 0; c < 4; c++) {
        float h = cb * hl[c] + (1.f - cb) * s[c];
        o[c] = f2bf(fmaxf(h, 0.f));
    }
    *((u16x4*)Hb + i) = o;
}

// ---------------------------------------------------------------------------
__global__ __launch_bounds__(256) void logsoftmax_k(const float* __restrict__ L,
                                                    float* __restrict__ out) {
    int row = blockIdx.x, tid = threadIdx.x;
    int lane = tid & 63, w = tid >> 6;
    const float* lr = L + (size_t)row * 512;
    float v0 = lr[tid], v1 = lr[tid + 256];
    __shared__ float bm[4], bs[4];
    float m = fmaxf(v0, v1);
    m = waveReduceMax(m);
    if (lane == 0) bm[w] = m;
    __syncthreads();
    float M = fmaxf(fmaxf(bm[0], bm[1]), fmaxf(bm[2], bm[3]));
    float s = expf(v0 - M) + expf(v1 - M);
    s = waveReduceSum(s);
    if (lane == 0) bs[w] = s;
    __syncthreads();
    float S = bs[0] + bs[1] + bs[2] + bs[3];
    float lse = M + logf(S);
    float* orow = out + (size_t)row * 512;
    orow[tid] = v0 - lse;
    orow[tid + 256] = v1 - lse;
}

// ---------------------------------------------------------------------------
extern "C" void kernel_launch(void* const* d_in, const int* in_sizes, int n_in,
                              void* d_out, int out_size, void* d_ws, size_t ws_size,
                              hipStream_t stream) {
    const float* x     = (const float*)d_in[0];
    const float* adj   = (const float*)d_in[1];
    const float* rmask = (const float*)d_in[2];
    const float* W_in  = (const float*)d_in[3];
    const float* b_in  = (const float*)d_in[4];
    const float* W_out = (const float*)d_in[5];
    const float* b_out = (const float*)d_in[6];
    const float* alpha = (const float*)d_in[7];
    const float* beta  = (const float*)d_in[8];
    float* out = (float*)d_out;

    const size_t MB = 1024 * 1024;
    char* wsb = (char*)d_ws;
    // [0,32):  simb bf16 -> (dead after topk) -> parts fp32 4x8MB -> logits [0,8)
    // [32,64): Mb bf16
    // [64,68): xn bf16    [68,72): xb bf16    [72,76): xbT bf16
    // [76,76.5): WinT     [76.5,77): WoutT
    // [77,85): parts4 (H_low partial, fp32)   [85,89): Hb bf16    [89): coef
    ushort* simb   = (ushort*)wsb;
    float*  parts  = (float*)wsb;
    float*  logits = (float*)wsb;
    ushort* Mb     = (ushort*)(wsb + 32 * MB);
    ushort* xn     = (ushort*)(wsb + 64 * MB);
    ushort* xb     = (ushort*)(wsb + 68 * MB);
    ushort* xbT    = (ushort*)(wsb + 72 * MB);
    ushort* WinT   = (ushort*)(wsb + 76 * MB);
    ushort* WoutT  = (ushort*)(wsb + 76 * MB + 512 * 1024);
    float*  parts4 = (float*)(wsb + 77 * MB);
    ushort* Hb     = (ushort*)(wsb + 85 * MB);
    float*  coef   = (float*)(wsb + 89 * MB);

    coef_k<<<1, 64, 0, stream>>>(alpha, beta, coef);

    // fused prep: xn/xb + x^T + both weight transposes (all independent)
    prep_fused<<<4096 + 512 + 128, 256, 0, stream>>>(
        x, xn, xb, xbT, W_in, WinT, W_out, WoutT);

    // sim = xn @ xn^T -> bf16 (symmetric: 528 upper-triangle tiles)
    gemm_sym<<<528, 256, 0, stream>>>(xn, simb);

    // combined masked adjacency M (bf16) — 512-thread blocks, 2 rows each
    topk_build_M<<<NROW / 2, 512, 0, stream>>>(simb, adj, rmask, coef, Mb);

    // split-K M@x (z<4) + H_low (z=4) in ONE dispatch (640 blocks)
    gemm_abT<3><<<dim3(4, 32, 5), 256, 0, stream>>>(
        Mb, NROW, xbT, NROW, 1024, 512, parts, nullptr, nullptr,
        xb, WinT, parts4);

    // H = relu(b*(H_low+bias) + (1-b)*sum parts) -> bf16
    reduce_relu<<<2048, 256, 0, stream>>>(parts, parts4, b_in, coef, Hb);

    // logits = H @ W_out + b_out
    gemm_abT<1><<<dim3(4, 32), 256, 0, stream>>>(
        Hb, 512, WoutT, 512, 512, 512, logits, nullptr, b_out,
        nullptr, nullptr, nullptr);

    logsoftmax_k<<<NROW, 256, 0, stream>>>(logits, out);
}

// Round 11
// 204.922 us; speedup vs baseline: 1.1819x; 1.0249x over previous
//
#include <hip/hip_runtime.h>
#include <hip/hip_bf16.h>
#include <stdint.h>

#define NROW 4096
#define FDIM 512

typedef short bf16x8 __attribute__((ext_vector_type(8)));
typedef float f32x4 __attribute__((ext_vector_type(4)));
typedef float f4 __attribute__((ext_vector_type(4)));
typedef ushort u16x4 __attribute__((ext_vector_type(4)));

#define NEG_INF (-__builtin_inff())

__device__ inline ushort f2bf(float f) {
    union { float f; uint32_t u; } c{f};
    uint32_t u = c.u;
    uint32_t r = (u + 0x7FFF + ((u >> 16) & 1)) >> 16;
    return (ushort)r;
}
__device__ inline float bf2f(ushort h) {
    union { uint32_t u; float f; } c{((uint32_t)h) << 16};
    return c.f;
}
// packed bf16 pair helpers: lo = element 0, hi = element 1
__device__ inline uint32_t cvt_pk_bf16(float lo, float hi) {
    uint32_t r;
    asm("v_cvt_pk_bf16_f32 %0, %1, %2" : "=v"(r) : "v"(lo), "v"(hi));
    return r;
}
__device__ inline float up0(uint32_t p) {
    union { uint32_t u; float f; } c{p << 16}; return c.f;
}
__device__ inline float up1(uint32_t p) {
    union { uint32_t u; float f; } c{p & 0xFFFF0000u}; return c.f;
}

__device__ inline float waveReduceMax(float v) {
    #pragma unroll
    for (int o = 32; o > 0; o >>= 1) v = fmaxf(v, __shfl_xor(v, o));
    return v;
}
__device__ inline float waveReduceSum(float v) {
    #pragma unroll
    for (int o = 32; o > 0; o >>= 1) v += __shfl_xor(v, o);
    return v;
}

// ---- sorting-network primitives (descending) -------------------------------
__device__ inline void CE(float& a, float& b) {
    float mx = fmaxf(a, b);
    b = fminf(a, b);
    a = mx;
}
// Batcher odd-even mergesort, 8 elements, descending, 19 comparators
__device__ inline void sort8(float (&l)[8]) {
    CE(l[0],l[1]); CE(l[2],l[3]); CE(l[4],l[5]); CE(l[6],l[7]);
    CE(l[0],l[2]); CE(l[1],l[3]); CE(l[4],l[6]); CE(l[5],l[7]);
    CE(l[1],l[2]); CE(l[5],l[6]);
    CE(l[0],l[4]); CE(l[1],l[5]); CE(l[2],l[6]); CE(l[3],l[7]);
    CE(l[2],l[4]); CE(l[3],l[5]);
    CE(l[1],l[2]); CE(l[3],l[4]); CE(l[5],l[6]);
}
// a, b sorted desc -> a = sorted desc top-8 of union (bitonic half-merge)
__device__ inline void mergeTop8(float (&a)[8], const float (&b)[8]) {
    float t[8];
    #pragma unroll
    for (int i = 0; i < 8; i++) t[i] = fmaxf(a[i], b[7 - i]);
    CE(t[0],t[4]); CE(t[1],t[5]); CE(t[2],t[6]); CE(t[3],t[7]);
    CE(t[0],t[2]); CE(t[1],t[3]); CE(t[4],t[6]); CE(t[5],t[7]);
    CE(t[0],t[1]); CE(t[2],t[3]); CE(t[4],t[5]); CE(t[6],t[7]);
    #pragma unroll
    for (int i = 0; i < 8; i++) a[i] = t[i];
}
// 8th-largest of union of two sorted-8 lists: min of the bitonic half-merge
__device__ inline float merge8th(const float (&a)[8], const float (&b)[8]) {
    float t0 = fminf(fmaxf(a[0], b[7]), fmaxf(a[1], b[6]));
    float t1 = fminf(fmaxf(a[2], b[5]), fmaxf(a[3], b[4]));
    float t2 = fminf(fmaxf(a[4], b[3]), fmaxf(a[5], b[2]));
    float t3 = fminf(fmaxf(a[6], b[1]), fmaxf(a[7], b[0]));
    return fminf(fminf(t0, t1), fminf(t2, t3));
}

#define GLL16(src, dst)                                                        \
    __builtin_amdgcn_global_load_lds(                                          \
        (const __attribute__((address_space(1))) void*)(src),                  \
        (__attribute__((address_space(3))) void*)(dst), 16, 0, 0)

// ---------------------------------------------------------------------------
__global__ __launch_bounds__(64) void coef_k(const float* __restrict__ alpha,
                                             const float* __restrict__ beta,
                                             float* __restrict__ coef) {
    if (threadIdx.x == 0) {
        float a0 = alpha[0], a1 = alpha[1], a2 = alpha[2];
        float m = fmaxf(a0, fmaxf(a1, a2));
        float e0 = expf(a0 - m), e1 = expf(a1 - m), e2 = expf(a2 - m);
        float s = e0 + e1 + e2;
        coef[0] = e0 / s; coef[1] = e1 / s; coef[2] = e2 / s;
        coef[3] = beta[0];
    }
}

// ---------------------------------------------------------------------------
// Fused preparation: all roles independent (transpose reads x directly).
__global__ __launch_bounds__(256) void prep_fused(
    const float* __restrict__ x, ushort* __restrict__ xn,
    ushort* __restrict__ xb, ushort* __restrict__ xbT,
    const float* __restrict__ W_in, ushort* __restrict__ WinT,
    const float* __restrict__ W_out, ushort* __restrict__ WoutT) {
    const int b = blockIdx.x;
    const int tid = threadIdx.x;
    __shared__ float b4[4];
    __shared__ ushort t[64][65];

    if (b < 4096) {
        const int row = b;
        int lane = tid & 63, w = tid >> 6;
        const float* xr = x + (size_t)row * FDIM;
        float v0 = xr[tid], v1 = xr[tid + 256];
        float ss = v0 * v0 + v1 * v1;
        ss = waveReduceSum(ss);
        if (lane == 0) b4[w] = ss;
        __syncthreads();
        float tot = b4[0] + b4[1] + b4[2] + b4[3];
        float inv = 1.f / fmaxf(sqrtf(tot), 1e-12f);
        size_t o = (size_t)row * FDIM + tid;
        xn[o] = f2bf(v0 * inv);  xn[o + 256] = f2bf(v1 * inv);
        xb[o] = f2bf(v0);        xb[o + 256] = f2bf(v1);
    } else if (b < 4608) {
        const int tb = b - 4096;
        const int c0 = (tb & 7) * 64, r0 = (tb >> 3) * 64;
        int lx = tid & 63, ly = tid >> 6;
        #pragma unroll
        for (int i = 0; i < 16; i++)
            t[ly + 4 * i][lx] = f2bf(x[(size_t)(r0 + ly + 4 * i) * FDIM + c0 + lx]);
        __syncthreads();
        #pragma unroll
        for (int i = 0; i < 16; i++)
            xbT[(size_t)(c0 + ly + 4 * i) * NROW + r0 + lx] = t[lx][ly + 4 * i];
    } else {
        const int cb = b - 4608;
        const float* Wf = (cb >> 6) ? W_out : W_in;
        ushort* WT = (cb >> 6) ? WoutT : WinT;
        const int idx = cb & 63;
        const int c0 = (idx & 7) * 64, r0 = (idx >> 3) * 64;
        int lx = tid & 63, ly = tid >> 6;
        #pragma unroll
        for (int i = 0; i < 16; i++)
            t[ly + 4 * i][lx] = f2bf(Wf[(size_t)(r0 + ly + 4 * i) * 512 + c0 + lx]);
        __syncthreads();
        #pragma unroll
        for (int i = 0; i < 16; i++)
            WT[(size_t)(c0 + ly + 4 * i) * 512 + r0 + lx] = t[lx][ly + 4 * i];
    }
}

// ---------------------------------------------------------------------------
// SYMMETRIC sim GEMM: simb = xn @ xn^T (bf16 out). 528 upper-triangle tiles;
// off-diagonal tiles written twice (normal + LDS-staged transposed).
__global__ __launch_bounds__(256) void gemm_sym(
    const ushort* __restrict__ A, ushort* __restrict__ C) {
    constexpr int BK = 64;
    constexpr int NT = 128 * BK;
    __shared__ __align__(16) ushort smem[128 * 130];
    ushort* As = smem;
    ushort* Bs = smem + NT;

    int bi = 0, rem = blockIdx.x;
    while (rem >= 32 - bi) { rem -= 32 - bi; bi++; }
    const int bj = bi + rem;
    const int m0 = bi * 128, n0 = bj * 128;

    const int tid = threadIdx.x;
    const int lane = tid & 63, w = tid >> 6;
    const int wr = w >> 1, wc = w & 1;

    f32x4 acc[4][4];
    #pragma unroll
    for (int mi = 0; mi < 4; mi++)
        #pragma unroll
        for (int ni = 0; ni < 4; ni++)
            #pragma unroll
            for (int r = 0; r < 4; r++) acc[mi][ni][r] = 0.f;

    for (int k0 = 0; k0 < FDIM; k0 += BK) {
        #pragma unroll
        for (int p = 0; p < 4; ++p) {
            int chunk = p * 256 + tid;
            int row = chunk / 8;
            int kc = chunk % 8;
            GLL16(A + (size_t)(m0 + row) * FDIM + k0 + kc * 8,
                  As + (size_t)(p * 256 + w * 64) * 8);
            GLL16(A + (size_t)(n0 + row) * FDIM + k0 + kc * 8,
                  Bs + (size_t)(p * 256 + w * 64) * 8);
        }
        __syncthreads();
        #pragma unroll
        for (int kf = 0; kf < BK / 32; ++kf) {
            const int ko = kf * 32 + (lane >> 4) * 8;
            bf16x8 av[4], bv[4];
            #pragma unroll
            for (int mi = 0; mi < 4; mi++)
                av[mi] = *(const bf16x8*)&As[(wr * 64 + mi * 16 + (lane & 15)) * BK + ko];
            #pragma unroll
            for (int ni = 0; ni < 4; ni++)
                bv[ni] = *(const bf16x8*)&Bs[(wc * 64 + ni * 16 + (lane & 15)) * BK + ko];
            #pragma unroll
            for (int mi = 0; mi < 4; mi++)
                #pragma unroll
                for (int ni = 0; ni < 4; ni++)
                    acc[mi][ni] = __builtin_amdgcn_mfma_f32_16x16x32_bf16(
                        av[mi], bv[ni], acc[mi][ni], 0, 0, 0);
        }
        __syncthreads();
    }

    #pragma unroll
    for (int mi = 0; mi < 4; mi++) {
        #pragma unroll
        for (int ni = 0; ni < 4; ni++) {
            int lcol = wc * 64 + ni * 16 + (lane & 15);
            #pragma unroll
            for (int r = 0; r < 4; r++) {
                int lrow = wr * 64 + mi * 16 + (lane >> 4) * 4 + r;
                ushort hv = f2bf(acc[mi][ni][r]);
                C[(size_t)(m0 + lrow) * NROW + n0 + lcol] = hv;
                smem[lrow * 130 + lcol] = hv;
            }
        }
    }

    if (bi != bj) {
        __syncthreads();
        const int wv = w;
        #pragma unroll 4
        for (int i = 0; i < 32; i++) {
            int r2 = wv * 32 + i;
            ushort a = smem[(lane * 2) * 130 + r2];
            ushort bb = smem[(lane * 2 + 1) * 130 + r2];
            uint32_t pk = (uint32_t)a | ((uint32_t)bb << 16);
            *(uint32_t*)&C[(size_t)(n0 + r2) * NROW + m0 + lane * 2] = pk;
        }
    }
}

// ---------------------------------------------------------------------------
// C = A(MxK) * B(NxK)^T, bf16 MFMA 16x16x32, 128x128 tile, 4 waves, BK=64.
// EPI 1: fp32 C + bias[col].
// EPI 3: split-K partials -> BF16 (r11: halves parts HBM traffic vs fp32).
//        z<4: K-chunk 1024 of M@x into Pb[z]; z==4: H_low=xb@WinT^T into Pb4.
template <int EPI>
__global__ __launch_bounds__(256) void gemm_abT(
    const ushort* __restrict__ A, int lda,
    const ushort* __restrict__ B, int ldb,
    int Kdim, int ldc,
    float* __restrict__ Cf, ushort* __restrict__ Pb,
    const float* __restrict__ bias,
    const ushort* __restrict__ A2, const ushort* __restrict__ B2,
    ushort* __restrict__ Pb4) {
    constexpr int BK = 64;
    constexpr int NT = 128 * BK;
    constexpr int CPR = BK / 8;
    constexpr int PASSES = (128 * CPR) / 256;
    __shared__ __align__(16) ushort smem[2 * NT];
    ushort* As = smem;
    ushort* Bs = smem + NT;

    int Kd = Kdim;
    if constexpr (EPI == 3) {
        if (blockIdx.z == 4) {
            A = A2; lda = FDIM; B = B2; ldb = FDIM; Kd = FDIM;
            Pb = Pb4;
        } else {
            A += (size_t)blockIdx.z * 1024;
            B += (size_t)blockIdx.z * 1024;
            Pb += (size_t)blockIdx.z * ((size_t)NROW * 512);
        }
    }

    const int tid = threadIdx.x;
    const int lane = tid & 63, w = tid >> 6;
    const int wr = w >> 1, wc = w & 1;
    const int m0 = blockIdx.y * 128;
    const int n0 = blockIdx.x * 128;

    f32x4 acc[4][4];
    #pragma unroll
    for (int mi = 0; mi < 4; mi++)
        #pragma unroll
        for (int ni = 0; ni < 4; ni++)
            #pragma unroll
            for (int r = 0; r < 4; r++) acc[mi][ni][r] = 0.f;

    for (int k0 = 0; k0 < Kd; k0 += BK) {
        #pragma unroll
        for (int p = 0; p < PASSES; ++p) {
            int chunk = p * 256 + tid;
            int row = chunk / CPR;
            int kc = chunk % CPR;
            const ushort* asrc = A + (size_t)(m0 + row) * lda + k0 + kc * 8;
            const ushort* bsrc = B + (size_t)(n0 + row) * ldb + k0 + kc * 8;
            ushort* abase = As + (size_t)(p * 256 + w * 64) * 8;
            ushort* bbase = Bs + (size_t)(p * 256 + w * 64) * 8;
            GLL16(asrc, abase);
            GLL16(bsrc, bbase);
        }
        __syncthreads();
        #pragma unroll
        for (int kf = 0; kf < BK / 32; ++kf) {
            const int ko = kf * 32 + (lane >> 4) * 8;
            bf16x8 av[4], bv[4];
            #pragma unroll
            for (int mi = 0; mi < 4; mi++)
                av[mi] = *(const bf16x8*)&As[(wr * 64 + mi * 16 + (lane & 15)) * BK + ko];
            #pragma unroll
            for (int ni = 0; ni < 4; ni++)
                bv[ni] = *(const bf16x8*)&Bs[(wc * 64 + ni * 16 + (lane & 15)) * BK + ko];
            #pragma unroll
            for (int mi = 0; mi < 4; mi++)
                #pragma unroll
                for (int ni = 0; ni < 4; ni++)
                    acc[mi][ni] = __builtin_amdgcn_mfma_f32_16x16x32_bf16(
                        av[mi], bv[ni], acc[mi][ni], 0, 0, 0);
        }
        __syncthreads();
    }

    #pragma unroll
    for (int mi = 0; mi < 4; mi++) {
        #pragma unroll
        for (int ni = 0; ni < 4; ni++) {
            int col = n0 + wc * 64 + ni * 16 + (lane & 15);
            #pragma unroll
            for (int r = 0; r < 4; r++) {
                int rowg = m0 + wr * 64 + mi * 16 + (lane >> 4) * 4 + r;
                size_t off = (size_t)rowg * ldc + col;
                float v = acc[mi][ni][r];
                if constexpr (EPI == 1) {
                    Cf[off] = v + bias[col];
                } else {
                    Pb[off] = f2bf(v);
                }
            }
        }
    }
}

// ---------------------------------------------------------------------------
// topk + build M.  512-thread blocks = 8 waves = 2 INDEPENDENT rows,
// 4 waves per row, lane owns 16 cols.  Per-wave program = r9/r10.
// r11: ONE barrier per hop (3 total, was 6) — the end-of-loop barrier was
// redundant: wl is indexed by hop k, so hop k+1 writes never race hop k
// reads.  The per-hop barrier convoy is the structure-invariant stall
// (r3-r10 all 128-148us); this is the minimum sync for this structure.
// Spill tripwire: WRITE_SIZE must stay 32768 KB (r4 lesson).
__global__ __launch_bounds__(512) void topk_build_M(
    const ushort* __restrict__ simb, const float* __restrict__ adj,
    const float* __restrict__ rmask, const float* __restrict__ coef,
    ushort* __restrict__ Mout) {
    const int tid = threadIdx.x;
    const int lane = tid & 63;
    const int w = tid >> 6;
    const int rloc = w >> 2;
    const int wv = w & 3;
    const int row = blockIdx.x * 2 + rloc;
    __shared__ float wl[2][3][4][8];

    const int cbase = wv * 1024 + lane * 4;
    const size_t hopstride = (size_t)NROW * NROW;

    const ushort* srow = simb + (size_t)row * NROW + cbase;
    const float* arow = adj + (size_t)row * NROW + cbase;
    const float* rrow = rmask + (size_t)row * NROW + cbase;

    uint2 svp[4];
    #pragma unroll
    for (int q = 0; q < 4; q++)
        svp[q] = *(const uint2*)(srow + q * 256);

    float macc[4][4];
    #pragma unroll
    for (int q = 0; q < 4; q++)
        #pragma unroll
        for (int c = 0; c < 4; c++) macc[q][c] = 0.f;

    #pragma unroll 1
    for (int k = 0; k < 3; ++k) {
        const float* ar = arow + (size_t)k * hopstride;
        const float* rr = rrow + (size_t)k * hopstride;

        f4 rv[4], a[4];
        #pragma unroll
        for (int q = 0; q < 4; q++) rv[q] = *(const f4*)(rr + q * 256);
        #pragma unroll
        for (int q = 0; q < 4; q++) a[q] = *(const f4*)(ar + q * 256);

        uint32_t rbits = 0;
        #pragma unroll
        for (int q = 0; q < 4; q++) {
            rbits |= (rv[q].x < 0.5f ? 1u : 0u) << (q * 4 + 0);
            rbits |= (rv[q].y < 0.5f ? 1u : 0u) << (q * 4 + 1);
            rbits |= (rv[q].z < 0.5f ? 1u : 0u) << (q * 4 + 2);
            rbits |= (rv[q].w < 0.5f ? 1u : 0u) << (q * 4 + 3);
        }

        uint2 avp[4];
        #pragma unroll
        for (int q = 0; q < 4; q++) {
            avp[q].x = cvt_pk_bf16(a[q].x, a[q].y);
            avp[q].y = cvt_pk_bf16(a[q].z, a[q].w);
        }

        float lo8[8], hi8[8];
        #pragma unroll
        for (int qq = 0; qq < 2; qq++) {
            lo8[qq * 4 + 0] = up0(avp[qq].x) * up0(svp[qq].x);
            lo8[qq * 4 + 1] = up1(avp[qq].x) * up1(svp[qq].x);
            lo8[qq * 4 + 2] = up0(avp[qq].y) * up0(svp[qq].y);
            lo8[qq * 4 + 3] = up1(avp[qq].y) * up1(svp[qq].y);
        }
        #pragma unroll
        for (int qq = 0; qq < 2; qq++) {
            const int q = 2 + qq;
            hi8[qq * 4 + 0] = up0(avp[q].x) * up0(svp[q].x);
            hi8[qq * 4 + 1] = up1(avp[q].x) * up1(svp[q].x);
            hi8[qq * 4 + 2] = up0(avp[q].y) * up0(svp[q].y);
            hi8[qq * 4 + 3] = up1(avp[q].y) * up1(svp[q].y);
        }
        sort8(lo8);
        sort8(hi8);
        mergeTop8(lo8, hi8);

        // wave top-8: 6-level merge tree
        #pragma unroll
        for (int lvl = 0; lvl < 6; lvl++) {
            float b[8];
            #pragma unroll
            for (int i = 0; i < 8; i++) b[i] = __shfl_xor(lo8[i], 1 << lvl);
            mergeTop8(lo8, b);
        }

        if (lane < 8) wl[rloc][k][wv][lane] = lo8[lane];
        __syncthreads();
        float b0[8], b1[8], b2[8];
        const int o0 = (wv + 1) & 3, o1 = (wv + 2) & 3, o2 = (wv + 3) & 3;
        #pragma unroll
        for (int i = 0; i < 8; i++) b0[i] = wl[rloc][k][o0][i];
        #pragma unroll
        for (int i = 0; i < 8; i++) b1[i] = wl[rloc][k][o1][i];
        #pragma unroll
        for (int i = 0; i < 8; i++) b2[i] = wl[rloc][k][o2][i];
        mergeTop8(lo8, b0);
        mergeTop8(lo8, b1);
        const float thr = merge8th(lo8, b2);

        const float ak = coef[k];
        const float aksq = ak * ak;
        #pragma unroll
        for (int q = 0; q < 4; q++) {
            float av0 = up0(avp[q].x), av1 = up1(avp[q].x);
            float av2 = up0(avp[q].y), av3 = up1(avp[q].y);
            float s0 = up0(svp[q].x), s1 = up1(svp[q].x);
            float s2 = up0(svp[q].y), s3 = up1(svp[q].y);
            bool m0 = ((rbits >> (q * 4 + 0)) & 1) || (av0 * s0 >= thr);
            bool m1 = ((rbits >> (q * 4 + 1)) & 1) || (av1 * s1 >= thr);
            bool m2 = ((rbits >> (q * 4 + 2)) & 1) || (av2 * s2 >= thr);
            bool m3 = ((rbits >> (q * 4 + 3)) & 1) || (av3 * s3 >= thr);
            macc[q][0] += m0 ? aksq * av0 : 0.f;
            macc[q][1] += m1 ? aksq * av1 : 0.f;
            macc[q][2] += m2 ? aksq * av2 : 0.f;
            macc[q][3] += m3 ? aksq * av3 : 0.f;
        }
        // NOTE: no end-of-loop barrier — wl[.][k+1][.] never aliases wl[.][k][.]
    }

    ushort* mrow = Mout + (size_t)row * NROW + cbase;
    #pragma unroll
    for (int q = 0; q < 4; q++) {
        u16x4 o;
        o[0] = f2bf(up0(svp[q].x) * macc[q][0]);
        o[1] = f2bf(up1(svp[q].x) * macc[q][1]);
        o[2] = f2bf(up0(svp[q].y) * macc[q][2]);
        o[3] = f2bf(up1(svp[q].y) * macc[q][3]);
        *(u16x4*)(mrow + q * 256) = o;
    }
}

// ---------------------------------------------------------------------------
// H = relu(cb*(parts4 + bias) + (1-cb)*sum_{z<4} parts[z]) -> bf16
// parts are bf16 now (r11): halves this kernel's read traffic.
__global__ __launch_bounds__(256) void reduce_relu(
    const ushort* __restrict__ parts, const ushort* __restrict__ parts4,
    const float* __restrict__ bias, const float* __restrict__ coef,
    ushort* __restrict__ Hb) {
    const size_t i = (size_t)blockIdx.x * 256 + threadIdx.x;  // u16x4 index
    f4 s = {0.f, 0.f, 0.f, 0.f};
    #pragma unroll
    for (int z = 0; z < 4; z++) {
        u16x4 p = *((const u16x4*)parts + (size_t)z * 524288 + i);
        #pragma unroll
        for (int c = 0; c < 4; c++) s[c] += bf2f(p[c]);
    }
    u16x4 h4 = *((const u16x4*)parts4 + i);
    f4 bi = ((const f4*)bias)[i & 127];
    float cb = coef[3];
    u16x4 o;
    #pragma unroll
    for (int c = 0; c < 4; c++) {
        float h = cb * (bf2f(h4[c]) + bi[c]) + (1.f - cb) * s[c];
        o[c] = f2bf(fmaxf(h, 0.f));
    }
    *((u16x4*)Hb + i) = o;
}

// ---------------------------------------------------------------------------
__global__ __launch_bounds__(256) void logsoftmax_k(const float* __restrict__ L,
                                                    float* __restrict__ out) {
    int row = blockIdx.x, tid = threadIdx.x;
    int lane = tid & 63, w = tid >> 6;
    const float* lr = L + (size_t)row * 512;
    float v0 = lr[tid], v1 = lr[tid + 256];
    __shared__ float bm[4], bs[4];
    float m = fmaxf(v0, v1);
    m = waveReduceMax(m);
    if (lane == 0) bm[w] = m;
    __syncthreads();
    float M = fmaxf(fmaxf(bm[0], bm[1]), fmaxf(bm[2], bm[3]));
    float s = expf(v0 - M) + expf(v1 - M);
    s = waveReduceSum(s);
    if (lane == 0) bs[w] = s;
    __syncthreads();
    float S = bs[0] + bs[1] + bs[2] + bs[3];
    float lse = M + logf(S);
    float* orow = out + (size_t)row * 512;
    orow[tid] = v0 - lse;
    orow[tid + 256] = v1 - lse;
}

// ---------------------------------------------------------------------------
extern "C" void kernel_launch(void* const* d_in, const int* in_sizes, int n_in,
                              void* d_out, int out_size, void* d_ws, size_t ws_size,
                              hipStream_t stream) {
    const float* x     = (const float*)d_in[0];
    const float* adj   = (const float*)d_in[1];
    const float* rmask = (const float*)d_in[2];
    const float* W_in  = (const float*)d_in[3];
    const float* b_in  = (const float*)d_in[4];
    const float* W_out = (const float*)d_in[5];
    const float* b_out = (const float*)d_in[6];
    const float* alpha = (const float*)d_in[7];
    const float* beta  = (const float*)d_in[8];
    float* out = (float*)d_out;

    const size_t MB = 1024 * 1024;
    char* wsb = (char*)d_ws;
    // [0,32):  simb bf16 (dead after topk) -> parts bf16 4x4MB [0,16)
    //          + parts4 bf16 [16,20) + logits fp32 [20,28)
    // [32,64): Mb bf16
    // [64,68): xn bf16    [68,72): xb bf16    [72,76): xbT bf16
    // [76,76.5): WinT     [76.5,77): WoutT
    // [85,89): Hb bf16    [89): coef
    ushort* simb   = (ushort*)wsb;
    ushort* parts  = (ushort*)wsb;
    ushort* parts4 = (ushort*)(wsb + 16 * MB);
    float*  logits = (float*)(wsb + 20 * MB);
    ushort* Mb     = (ushort*)(wsb + 32 * MB);
    ushort* xn     = (ushort*)(wsb + 64 * MB);
    ushort* xb     = (ushort*)(wsb + 68 * MB);
    ushort* xbT    = (ushort*)(wsb + 72 * MB);
    ushort* WinT   = (ushort*)(wsb + 76 * MB);
    ushort* WoutT  = (ushort*)(wsb + 76 * MB + 512 * 1024);
    ushort* Hb     = (ushort*)(wsb + 85 * MB);
    float*  coef   = (float*)(wsb + 89 * MB);

    coef_k<<<1, 64, 0, stream>>>(alpha, beta, coef);

    // fused prep: xn/xb + x^T + both weight transposes (all independent)
    prep_fused<<<4096 + 512 + 128, 256, 0, stream>>>(
        x, xn, xb, xbT, W_in, WinT, W_out, WoutT);

    // sim = xn @ xn^T -> bf16 (symmetric: 528 upper-triangle tiles)
    gemm_sym<<<528, 256, 0, stream>>>(xn, simb);

    // combined masked adjacency M (bf16) — 512-thread blocks, 2 rows each
    topk_build_M<<<NROW / 2, 512, 0, stream>>>(simb, adj, rmask, coef, Mb);

    // split-K M@x (z<4) + H_low (z=4) in ONE dispatch; bf16 partials
    gemm_abT<3><<<dim3(4, 32, 5), 256, 0, stream>>>(
        Mb, NROW, xbT, NROW, 1024, 512, nullptr, parts, nullptr,
        xb, WinT, parts4);

    // H = relu(b*(H_low+bias) + (1-b)*sum parts) -> bf16
    reduce_relu<<<2048, 256, 0, stream>>>(parts, parts4, b_in, coef, Hb);

    // logits = H @ W_out + b_out
    gemm_abT<1><<<dim3(4, 32), 256, 0, stream>>>(
        Hb, 512, WoutT, 512, 512, 512, logits, nullptr, b_out,
        nullptr, nullptr, nullptr);

    logsoftmax_k<<<NROW, 256, 0, stream>>>(logits, out);
}